// Round 1
// baseline (369.820 us; speedup 1.0000x reference)
//
#include <hip/hip_runtime.h>

#define NEG_SLOPE 0.2f
static constexpr int IN_F = 128;   // input feature dim
static constexpr int NHEAD = 4;
static constexpr int CH = 64;      // channels per head
static constexpr int HC = 256;     // NHEAD*CH

static __host__ size_t align256(size_t v) { return (v + 255) & ~((size_t)255); }

// ---------------- GEMM: h[N,256] = x[N,128] @ W[128,256] (fp32) -------------
__global__ __launch_bounds__(256) void gemm_kernel(
    const float* __restrict__ x, const float* __restrict__ W,
    float* __restrict__ h, int N)
{
    __shared__ float As[64][65];   // As[k][r] (transposed), +1 pad vs bank conflicts
    __shared__ float Bs[64][64];   // Bs[k][c]
    const int t = threadIdx.x;
    const int m0 = blockIdx.x * 64;
    const int n0 = blockIdx.y * 64;
    const int tc = t & 15;         // col quad 0..15
    const int tr = t >> 4;         // row quad 0..15

    float acc[4][4] = {};

    for (int kt = 0; kt < 2; ++kt) {
        // stage A tile: 64 rows x 64 k, transposed into As[k][r]
        #pragma unroll
        for (int u = 0; u < 4; ++u) {
            int f = t + 256 * u;          // float4 index 0..1023
            int r = f >> 4;               // 0..63
            int k4 = (f & 15) * 4;        // 0..60
            int row = m0 + r;
            float4 v = make_float4(0.f, 0.f, 0.f, 0.f);
            if (row < N)
                v = *(const float4*)(x + (size_t)row * IN_F + kt * 64 + k4);
            As[k4 + 0][r] = v.x;
            As[k4 + 1][r] = v.y;
            As[k4 + 2][r] = v.z;
            As[k4 + 3][r] = v.w;
        }
        // stage B tile: 64 k x 64 cols
        #pragma unroll
        for (int u = 0; u < 4; ++u) {
            int f = t + 256 * u;
            int k = f >> 4;               // 0..63
            int c4 = (f & 15) * 4;        // 0..60
            float4 v = *(const float4*)(W + (size_t)(kt * 64 + k) * HC + n0 + c4);
            *(float4*)&Bs[k][c4] = v;
        }
        __syncthreads();
        #pragma unroll 8
        for (int k = 0; k < 64; ++k) {
            float a0 = As[k][4 * tr + 0];
            float a1 = As[k][4 * tr + 1];
            float a2 = As[k][4 * tr + 2];
            float a3 = As[k][4 * tr + 3];
            float4 b = *(const float4*)&Bs[k][4 * tc];
            acc[0][0] += a0 * b.x; acc[0][1] += a0 * b.y; acc[0][2] += a0 * b.z; acc[0][3] += a0 * b.w;
            acc[1][0] += a1 * b.x; acc[1][1] += a1 * b.y; acc[1][2] += a1 * b.z; acc[1][3] += a1 * b.w;
            acc[2][0] += a2 * b.x; acc[2][1] += a2 * b.y; acc[2][2] += a2 * b.z; acc[2][3] += a2 * b.w;
            acc[3][0] += a3 * b.x; acc[3][1] += a3 * b.y; acc[3][2] += a3 * b.z; acc[3][3] += a3 * b.w;
        }
        __syncthreads();
    }
    #pragma unroll
    for (int i = 0; i < 4; ++i) {
        int row = m0 + 4 * tr + i;
        if (row < N) {
            float4 v = make_float4(acc[i][0], acc[i][1], acc[i][2], acc[i][3]);
            *(float4*)(h + (size_t)row * HC + n0 + 4 * tc) = v;
        }
    }
}

// ------------- per-node attention dots: a_src[n,h], a_dst[n,h] --------------
// one wave per node; lane l covers head l>>4, channels 4*(l&15)..+3
__global__ __launch_bounds__(256) void att_kernel(
    const float* __restrict__ h,
    const float* __restrict__ att_src, const float* __restrict__ att_dst,
    float* __restrict__ a_src, float* __restrict__ a_dst, int N)
{
    int node = (int)((blockIdx.x * (size_t)blockDim.x + threadIdx.x) >> 6);
    int l = threadIdx.x & 63;
    if (node >= N) return;
    float4 hv = *(const float4*)(h + (size_t)node * HC + 4 * l);
    float4 as = *(const float4*)(att_src + 4 * l);
    float4 ad = *(const float4*)(att_dst + 4 * l);
    float ps = hv.x * as.x + hv.y * as.y + hv.z * as.z + hv.w * as.w;
    float pd = hv.x * ad.x + hv.y * ad.y + hv.z * ad.z + hv.w * ad.w;
    #pragma unroll
    for (int off = 1; off < 16; off <<= 1) {
        ps += __shfl_xor(ps, off, 64);
        pd += __shfl_xor(pd, off, 64);
    }
    if ((l & 15) == 0) {
        a_src[(size_t)node * NHEAD + (l >> 4)] = ps;
        a_dst[(size_t)node * NHEAD + (l >> 4)] = pd;
    }
}

// ---------------------------- CSR construction ------------------------------
__global__ void init_deg(int* deg, int* rowptr, int N, int Etot)
{
    int i = blockIdx.x * blockDim.x + threadIdx.x;
    if (i < N) deg[i] = 1;            // self loop
    if (i == 0) rowptr[N] = Etot;
}

__global__ void count_kernel(const int* __restrict__ dst, int* deg, int E)
{
    int e = blockIdx.x * blockDim.x + threadIdx.x;
    if (e < E) atomicAdd(&deg[dst[e]], 1);
}

// block-level exclusive scan, 256 elems/block
__global__ __launch_bounds__(256) void scan1(const int* __restrict__ deg,
                                             int* __restrict__ rowptr,
                                             int* __restrict__ bsums, int N)
{
    __shared__ int sm[256];
    int t = threadIdx.x;
    int i = blockIdx.x * 256 + t;
    int v = (i < N) ? deg[i] : 0;
    sm[t] = v;
    __syncthreads();
    #pragma unroll
    for (int off = 1; off < 256; off <<= 1) {
        int a = sm[t];
        int b = (t >= off) ? sm[t - off] : 0;
        __syncthreads();
        sm[t] = a + b;
        __syncthreads();
    }
    int incl = sm[t];
    if (i < N) rowptr[i] = incl - v;           // block-local exclusive
    if (t == 255) bsums[blockIdx.x] = incl;    // block total
}

__global__ __launch_bounds__(256) void scan2(int* bsums, int nb)
{
    __shared__ int sm[256];
    int t = threadIdx.x;
    int v = (t < nb) ? bsums[t] : 0;
    sm[t] = v;
    __syncthreads();
    #pragma unroll
    for (int off = 1; off < 256; off <<= 1) {
        int a = sm[t];
        int b = (t >= off) ? sm[t - off] : 0;
        __syncthreads();
        sm[t] = a + b;
        __syncthreads();
    }
    if (t < nb) bsums[t] = sm[t] - v;          // exclusive over blocks
}

__global__ void scan3(int* rowptr, int* cursor, const int* __restrict__ bsums, int N)
{
    int i = blockIdx.x * blockDim.x + threadIdx.x;
    if (i < N) {
        int r = rowptr[i] + bsums[i >> 8];
        rowptr[i] = r;
        cursor[i] = r;
    }
}

__global__ void scatter_kernel(const int* __restrict__ src, const int* __restrict__ dst,
                               int* cursor, int* __restrict__ csr_src, int E, int N)
{
    int t = blockIdx.x * blockDim.x + threadIdx.x;
    if (t < E) {
        int d = dst[t];
        int pos = atomicAdd(&cursor[d], 1);
        csr_src[pos] = src[t];
    } else if (t < E + N) {
        int d = t - E;                          // self loop
        int pos = atomicAdd(&cursor[d], 1);
        csr_src[pos] = d;
    }
}

// ----------------- per-destination softmax + weighted aggregate -------------
// one wave per node; lane l: head hd=l>>4, channels 4*(l&15)..+3
__global__ __launch_bounds__(256) void aggregate_kernel(
    const float* __restrict__ h, const float* __restrict__ a_src,
    const float* __restrict__ a_dst, const int* __restrict__ rowptr,
    const int* __restrict__ csr_src, const float* __restrict__ bias,
    float* __restrict__ out, int N)
{
    int node = (int)((blockIdx.x * (size_t)blockDim.x + threadIdx.x) >> 6);
    int l = threadIdx.x & 63;
    if (node >= N) return;
    int start = rowptr[node];
    int end = rowptr[node + 1];

    float4 ad4 = *(const float4*)(a_dst + (size_t)node * NHEAD);
    float ad[4] = { ad4.x, ad4.y, ad4.z, ad4.w };

    // phase 1: online softmax stats per head, edges strided across lanes
    float m[4] = { -1e30f, -1e30f, -1e30f, -1e30f };
    float s[4] = { 0.f, 0.f, 0.f, 0.f };
    for (int k = start + l; k < end; k += 64) {
        int sj = csr_src[k];
        float4 a4 = *(const float4*)(a_src + (size_t)sj * NHEAD);
        float ev[4] = { a4.x + ad[0], a4.y + ad[1], a4.z + ad[2], a4.w + ad[3] };
        #pragma unroll
        for (int hh = 0; hh < 4; ++hh) {
            float e = ev[hh];
            e = (e >= 0.f) ? e : NEG_SLOPE * e;
            float nm = fmaxf(m[hh], e);
            s[hh] = s[hh] * __expf(m[hh] - nm) + __expf(e - nm);
            m[hh] = nm;
        }
    }
    // merge stats across all 64 lanes
    #pragma unroll
    for (int off = 1; off < 64; off <<= 1) {
        #pragma unroll
        for (int hh = 0; hh < 4; ++hh) {
            float m2 = __shfl_xor(m[hh], off, 64);
            float s2 = __shfl_xor(s[hh], off, 64);
            float nm = fmaxf(m[hh], m2);
            s[hh] = s[hh] * __expf(m[hh] - nm) + s2 * __expf(m2 - nm);
            m[hh] = nm;
        }
    }

    int hd = l >> 4;
    float mh  = (hd == 0) ? m[0] : (hd == 1) ? m[1] : (hd == 2) ? m[2] : m[3];
    float sh  = (hd == 0) ? s[0] : (hd == 1) ? s[1] : (hd == 2) ? s[2] : s[3];
    float adh = (hd == 0) ? ad[0] : (hd == 1) ? ad[1] : (hd == 2) ? ad[2] : ad[3];
    float inv = 1.0f / sh;

    // phase 2: weighted accumulate; wave reads h[src] as contiguous 1KB
    float4 acc = make_float4(0.f, 0.f, 0.f, 0.f);
    for (int k = start; k < end; ++k) {
        int sj = csr_src[k];
        float a = a_src[(size_t)sj * NHEAD + hd];
        float e = a + adh;
        e = (e >= 0.f) ? e : NEG_SLOPE * e;
        float alpha = __expf(e - mh) * inv;
        float4 hv = *(const float4*)(h + (size_t)sj * HC + 4 * l);
        acc.x += alpha * hv.x;
        acc.y += alpha * hv.y;
        acc.z += alpha * hv.z;
        acc.w += alpha * hv.w;
    }
    // reduce over heads: lanes l, l^16, l^32, l^48 hold same channels
    #pragma unroll
    for (int off = 16; off < 64; off <<= 1) {
        acc.x += __shfl_xor(acc.x, off, 64);
        acc.y += __shfl_xor(acc.y, off, 64);
        acc.z += __shfl_xor(acc.z, off, 64);
        acc.w += __shfl_xor(acc.w, off, 64);
    }
    if (l < 16) {
        float4 b4 = *(const float4*)(bias + 4 * l);
        float4 o;
        o.x = acc.x * 0.25f + b4.x;
        o.y = acc.y * 0.25f + b4.y;
        o.z = acc.z * 0.25f + b4.z;
        o.w = acc.w * 0.25f + b4.w;
        o.x = (o.x > 0.f) ? o.x : (__expf(o.x) - 1.f);
        o.y = (o.y > 0.f) ? o.y : (__expf(o.y) - 1.f);
        o.z = (o.z > 0.f) ? o.z : (__expf(o.z) - 1.f);
        o.w = (o.w > 0.f) ? o.w : (__expf(o.w) - 1.f);
        *(float4*)(out + (size_t)node * CH + 4 * l) = o;
    }
}

extern "C" void kernel_launch(void* const* d_in, const int* in_sizes, int n_in,
                              void* d_out, int out_size, void* d_ws, size_t ws_size,
                              hipStream_t stream)
{
    const float* x         = (const float*)d_in[0];
    const int*   edge_idx  = (const int*)d_in[1];
    const float* W         = (const float*)d_in[2];
    const float* att_src   = (const float*)d_in[3];
    const float* att_dst   = (const float*)d_in[4];
    const float* bias      = (const float*)d_in[5];
    float* out = (float*)d_out;

    const int N = in_sizes[0] / IN_F;
    const int E = in_sizes[1] / 2;
    const int Etot = E + N;
    const int* srcp = edge_idx;
    const int* dstp = edge_idx + E;

    char* ws = (char*)d_ws;
    size_t off = 0;
    float* h      = (float*)(ws + off); off += align256((size_t)N * HC * sizeof(float));
    float* a_src  = (float*)(ws + off); off += align256((size_t)N * NHEAD * sizeof(float));
    float* a_dst  = (float*)(ws + off); off += align256((size_t)N * NHEAD * sizeof(float));
    int*   deg    = (int*)(ws + off);   off += align256((size_t)N * sizeof(int));
    int*   rowptr = (int*)(ws + off);   off += align256(((size_t)N + 1) * sizeof(int));
    int*   cursor = (int*)(ws + off);   off += align256((size_t)N * sizeof(int));
    int*   csrs   = (int*)(ws + off);   off += align256((size_t)Etot * sizeof(int));
    int*   bsums  = (int*)(ws + off);   off += align256(256 * sizeof(int));
    (void)ws_size; (void)n_in; (void)out_size;

    dim3 gg((N + 63) / 64, HC / 64);
    gemm_kernel<<<gg, 256, 0, stream>>>(x, W, h, N);
    att_kernel<<<((size_t)N * 64 + 255) / 256, 256, 0, stream>>>(h, att_src, att_dst, a_src, a_dst, N);
    init_deg<<<(N + 255) / 256, 256, 0, stream>>>(deg, rowptr, N, Etot);
    count_kernel<<<(E + 255) / 256, 256, 0, stream>>>(dstp, deg, E);
    int nb = (N + 255) / 256;  // 196 <= 256
    scan1<<<nb, 256, 0, stream>>>(deg, rowptr, bsums, N);
    scan2<<<1, 256, 0, stream>>>(bsums, nb);
    scan3<<<(N + 255) / 256, 256, 0, stream>>>(rowptr, cursor, bsums, N);
    scatter_kernel<<<(Etot + 255) / 256, 256, 0, stream>>>(srcp, dstp, cursor, csrs, E, N);
    aggregate_kernel<<<((size_t)N * 64 + 255) / 256, 256, 0, stream>>>(
        h, a_src, a_dst, rowptr, csrs, bias, out, N);
}

// Round 2
// 344.000 us; speedup vs baseline: 1.0751x; 1.0751x over previous
//
#include <hip/hip_runtime.h>

#define NEG_SLOPE 0.2f
static constexpr int IN_F = 128;   // input feature dim
static constexpr int NHEAD = 4;
static constexpr int CH = 64;      // channels per head
static constexpr int HC = 256;     // NHEAD*CH

static __host__ size_t align256(size_t v) { return (v + 255) & ~((size_t)255); }

__device__ inline ushort f2bf(float f) {          // round-to-nearest-even fp32->bf16
    unsigned u = __float_as_uint(f);
    unsigned r = u + 0x7FFFu + ((u >> 16) & 1u);
    return (ushort)(r >> 16);
}
__device__ inline float bf2f(ushort s) { return __uint_as_float(((unsigned)s) << 16); }

// ---- GEMM: h[N,256] = x[N,128] @ W[128,256]; fused att dots + bf16 h store --
// grid.y = 4 tiles of 64 cols; each n-tile is exactly one head.
__global__ __launch_bounds__(256) void gemm_att_kernel(
    const float* __restrict__ x, const float* __restrict__ W,
    const float* __restrict__ att_src, const float* __restrict__ att_dst,
    ushort* __restrict__ hb, float* __restrict__ a_src, float* __restrict__ a_dst,
    int N)
{
    __shared__ float As[64][65];   // As[k][r] (transposed), +1 pad vs bank conflicts
    __shared__ float Bs[64][64];   // Bs[k][c]
    const int t = threadIdx.x;
    const int m0 = blockIdx.x * 64;
    const int n0 = blockIdx.y * 64;
    const int head = blockIdx.y;
    const int tc = t & 15;         // col quad 0..15
    const int tr = t >> 4;         // row quad 0..15

    float acc[4][4] = {};

    for (int kt = 0; kt < 2; ++kt) {
        #pragma unroll
        for (int u = 0; u < 4; ++u) {
            int f = t + 256 * u;          // float4 index 0..1023
            int r = f >> 4;               // 0..63
            int k4 = (f & 15) * 4;        // 0..60
            int row = m0 + r;
            float4 v = make_float4(0.f, 0.f, 0.f, 0.f);
            if (row < N)
                v = *(const float4*)(x + (size_t)row * IN_F + kt * 64 + k4);
            As[k4 + 0][r] = v.x;
            As[k4 + 1][r] = v.y;
            As[k4 + 2][r] = v.z;
            As[k4 + 3][r] = v.w;
        }
        #pragma unroll
        for (int u = 0; u < 4; ++u) {
            int f = t + 256 * u;
            int k = f >> 4;               // 0..63
            int c4 = (f & 15) * 4;        // 0..60
            float4 v = *(const float4*)(W + (size_t)(kt * 64 + k) * HC + n0 + c4);
            *(float4*)&Bs[k][c4] = v;
        }
        __syncthreads();
        #pragma unroll 8
        for (int k = 0; k < 64; ++k) {
            float a0 = As[k][4 * tr + 0];
            float a1 = As[k][4 * tr + 1];
            float a2 = As[k][4 * tr + 2];
            float a3 = As[k][4 * tr + 3];
            float4 b = *(const float4*)&Bs[k][4 * tc];
            acc[0][0] += a0 * b.x; acc[0][1] += a0 * b.y; acc[0][2] += a0 * b.z; acc[0][3] += a0 * b.w;
            acc[1][0] += a1 * b.x; acc[1][1] += a1 * b.y; acc[1][2] += a1 * b.z; acc[1][3] += a1 * b.w;
            acc[2][0] += a2 * b.x; acc[2][1] += a2 * b.y; acc[2][2] += a2 * b.z; acc[2][3] += a2 * b.w;
            acc[3][0] += a3 * b.x; acc[3][1] += a3 * b.y; acc[3][2] += a3 * b.z; acc[3][3] += a3 * b.w;
        }
        __syncthreads();
    }

    // epilogue: bf16 h store + per-(row,head) attention dots
    float4 vs = *(const float4*)(att_src + n0 + 4 * tc);
    float4 vd = *(const float4*)(att_dst + n0 + 4 * tc);
    #pragma unroll
    for (int i = 0; i < 4; ++i) {
        int row = m0 + 4 * tr + i;
        float ps = acc[i][0] * vs.x + acc[i][1] * vs.y + acc[i][2] * vs.z + acc[i][3] * vs.w;
        float pd = acc[i][0] * vd.x + acc[i][1] * vd.y + acc[i][2] * vd.z + acc[i][3] * vd.w;
        #pragma unroll
        for (int off = 1; off < 16; off <<= 1) {   // reduce over the 16 tc lanes
            ps += __shfl_xor(ps, off, 64);
            pd += __shfl_xor(pd, off, 64);
        }
        if (row < N) {
            ushort4 o;
            o.x = f2bf(acc[i][0]); o.y = f2bf(acc[i][1]);
            o.z = f2bf(acc[i][2]); o.w = f2bf(acc[i][3]);
            *(ushort4*)(hb + (size_t)row * HC + n0 + 4 * tc) = o;
            if (tc == 0) {
                a_src[(size_t)row * NHEAD + head] = ps;
                a_dst[(size_t)row * NHEAD + head] = pd;
            }
        }
    }
}

// ---------------------------- CSR construction ------------------------------
__global__ void init_deg(int* deg, int* rowptr, int N, int Etot)
{
    int i = blockIdx.x * blockDim.x + threadIdx.x;
    if (i < N) deg[i] = 1;            // self loop
    if (i == 0) rowptr[N] = Etot;
}

__global__ void count_kernel(const int* __restrict__ dst, int* deg, int E)
{
    int e = blockIdx.x * blockDim.x + threadIdx.x;
    if (e < E) atomicAdd(&deg[dst[e]], 1);
}

// block-level exclusive scan, 256 elems/block
__global__ __launch_bounds__(256) void scan1(const int* __restrict__ deg,
                                             int* __restrict__ rowptr,
                                             int* __restrict__ bsums, int N)
{
    __shared__ int sm[256];
    int t = threadIdx.x;
    int i = blockIdx.x * 256 + t;
    int v = (i < N) ? deg[i] : 0;
    sm[t] = v;
    __syncthreads();
    #pragma unroll
    for (int off = 1; off < 256; off <<= 1) {
        int a = sm[t];
        int b = (t >= off) ? sm[t - off] : 0;
        __syncthreads();
        sm[t] = a + b;
        __syncthreads();
    }
    int incl = sm[t];
    if (i < N) rowptr[i] = incl - v;           // block-local exclusive
    if (t == 255) bsums[blockIdx.x] = incl;    // block total
}

__global__ __launch_bounds__(256) void scan2(int* bsums, int nb)
{
    __shared__ int sm[256];
    int t = threadIdx.x;
    int v = (t < nb) ? bsums[t] : 0;
    sm[t] = v;
    __syncthreads();
    #pragma unroll
    for (int off = 1; off < 256; off <<= 1) {
        int a = sm[t];
        int b = (t >= off) ? sm[t - off] : 0;
        __syncthreads();
        sm[t] = a + b;
        __syncthreads();
    }
    if (t < nb) bsums[t] = sm[t] - v;          // exclusive over blocks
}

__global__ void scan3(int* rowptr, int* cursor, const int* __restrict__ bsums, int N)
{
    int i = blockIdx.x * blockDim.x + threadIdx.x;
    if (i < N) {
        int r = rowptr[i] + bsums[i >> 8];
        rowptr[i] = r;
        cursor[i] = r;
    }
}

__global__ void scatter_kernel(const int* __restrict__ src, const int* __restrict__ dst,
                               int* cursor, int* __restrict__ csr_src, int E, int N)
{
    int t = blockIdx.x * blockDim.x + threadIdx.x;
    if (t < E) {
        int d = dst[t];
        int pos = atomicAdd(&cursor[d], 1);
        csr_src[pos] = src[t];
    } else if (t < E + N) {
        int d = t - E;                          // self loop
        int pos = atomicAdd(&cursor[d], 1);
        csr_src[pos] = d;
    }
}

// ----------------- per-destination softmax + weighted aggregate -------------
// one wave per node; lane l: head hd=l>>4, channels 4*(l&15)..+3 (bf16 h)
__global__ __launch_bounds__(256) void aggregate_kernel(
    const ushort* __restrict__ hb, const float* __restrict__ a_src,
    const float* __restrict__ a_dst, const int* __restrict__ rowptr,
    const int* __restrict__ csr_src, const float* __restrict__ bias,
    float* __restrict__ out, int N)
{
    int node = (int)((blockIdx.x * (size_t)blockDim.x + threadIdx.x) >> 6);
    int l = threadIdx.x & 63;
    if (node >= N) return;
    int start = rowptr[node];
    int end = rowptr[node + 1];

    float4 ad4 = *(const float4*)(a_dst + (size_t)node * NHEAD);
    float ad[4] = { ad4.x, ad4.y, ad4.z, ad4.w };

    // phase 1: online softmax stats per head, edges strided across lanes
    float m[4] = { -1e30f, -1e30f, -1e30f, -1e30f };
    float s[4] = { 0.f, 0.f, 0.f, 0.f };
    for (int k = start + l; k < end; k += 64) {
        int sj = csr_src[k];
        float4 a4 = *(const float4*)(a_src + (size_t)sj * NHEAD);
        float ev[4] = { a4.x + ad[0], a4.y + ad[1], a4.z + ad[2], a4.w + ad[3] };
        #pragma unroll
        for (int hh = 0; hh < 4; ++hh) {
            float e = ev[hh];
            e = (e >= 0.f) ? e : NEG_SLOPE * e;
            float nm = fmaxf(m[hh], e);
            s[hh] = s[hh] * __expf(m[hh] - nm) + __expf(e - nm);
            m[hh] = nm;
        }
    }
    #pragma unroll
    for (int off = 1; off < 64; off <<= 1) {
        #pragma unroll
        for (int hh = 0; hh < 4; ++hh) {
            float m2 = __shfl_xor(m[hh], off, 64);
            float s2 = __shfl_xor(s[hh], off, 64);
            float nm = fmaxf(m[hh], m2);
            s[hh] = s[hh] * __expf(m[hh] - nm) + s2 * __expf(m2 - nm);
            m[hh] = nm;
        }
    }

    int hd = l >> 4;
    float mh  = (hd == 0) ? m[0] : (hd == 1) ? m[1] : (hd == 2) ? m[2] : m[3];
    float sh  = (hd == 0) ? s[0] : (hd == 1) ? s[1] : (hd == 2) ? s[2] : s[3];
    float adh = (hd == 0) ? ad[0] : (hd == 1) ? ad[1] : (hd == 2) ? ad[2] : ad[3];
    float inv = 1.0f / sh;

    // phase 2: weighted accumulate; wave reads h[src] as contiguous 512B (bf16)
    float4 acc = make_float4(0.f, 0.f, 0.f, 0.f);
    int sj = csr_src[start];                      // deg >= 1 (self loop)
    for (int k = start; k < end; ++k) {
        int sjn = (k + 1 < end) ? csr_src[k + 1] : 0;   // prefetch next index
        float a = a_src[(size_t)sj * NHEAD + hd];
        float e = a + adh;
        e = (e >= 0.f) ? e : NEG_SLOPE * e;
        float alpha = __expf(e - mh) * inv;
        ushort4 hv = *(const ushort4*)(hb + (size_t)sj * HC + 4 * l);
        acc.x += alpha * bf2f(hv.x);
        acc.y += alpha * bf2f(hv.y);
        acc.z += alpha * bf2f(hv.z);
        acc.w += alpha * bf2f(hv.w);
        sj = sjn;
    }
    // reduce over heads: lanes l, l^16, l^32, l^48 hold same channels
    #pragma unroll
    for (int off = 16; off < 64; off <<= 1) {
        acc.x += __shfl_xor(acc.x, off, 64);
        acc.y += __shfl_xor(acc.y, off, 64);
        acc.z += __shfl_xor(acc.z, off, 64);
        acc.w += __shfl_xor(acc.w, off, 64);
    }
    if (l < 16) {
        float4 b4 = *(const float4*)(bias + 4 * l);
        float4 o;
        o.x = acc.x * 0.25f + b4.x;
        o.y = acc.y * 0.25f + b4.y;
        o.z = acc.z * 0.25f + b4.z;
        o.w = acc.w * 0.25f + b4.w;
        o.x = (o.x > 0.f) ? o.x : (__expf(o.x) - 1.f);
        o.y = (o.y > 0.f) ? o.y : (__expf(o.y) - 1.f);
        o.z = (o.z > 0.f) ? o.z : (__expf(o.z) - 1.f);
        o.w = (o.w > 0.f) ? o.w : (__expf(o.w) - 1.f);
        *(float4*)(out + (size_t)node * CH + 4 * l) = o;
    }
}

extern "C" void kernel_launch(void* const* d_in, const int* in_sizes, int n_in,
                              void* d_out, int out_size, void* d_ws, size_t ws_size,
                              hipStream_t stream)
{
    const float* x         = (const float*)d_in[0];
    const int*   edge_idx  = (const int*)d_in[1];
    const float* W         = (const float*)d_in[2];
    const float* att_src   = (const float*)d_in[3];
    const float* att_dst   = (const float*)d_in[4];
    const float* bias      = (const float*)d_in[5];
    float* out = (float*)d_out;

    const int N = in_sizes[0] / IN_F;
    const int E = in_sizes[1] / 2;
    const int Etot = E + N;
    const int* srcp = edge_idx;
    const int* dstp = edge_idx + E;

    char* ws = (char*)d_ws;
    size_t off = 0;
    ushort* hb    = (ushort*)(ws + off); off += align256((size_t)N * HC * sizeof(ushort));
    float* a_src  = (float*)(ws + off);  off += align256((size_t)N * NHEAD * sizeof(float));
    float* a_dst  = (float*)(ws + off);  off += align256((size_t)N * NHEAD * sizeof(float));
    int*   deg    = (int*)(ws + off);    off += align256((size_t)N * sizeof(int));
    int*   rowptr = (int*)(ws + off);    off += align256(((size_t)N + 1) * sizeof(int));
    int*   cursor = (int*)(ws + off);    off += align256((size_t)N * sizeof(int));
    int*   csrs   = (int*)(ws + off);    off += align256((size_t)Etot * sizeof(int));
    int*   bsums  = (int*)(ws + off);    off += align256(256 * sizeof(int));
    (void)ws_size; (void)n_in; (void)out_size;

    dim3 gg((N + 63) / 64, HC / 64);
    gemm_att_kernel<<<gg, 256, 0, stream>>>(x, W, att_src, att_dst, hb, a_src, a_dst, N);
    init_deg<<<(N + 255) / 256, 256, 0, stream>>>(deg, rowptr, N, Etot);
    count_kernel<<<(E + 255) / 256, 256, 0, stream>>>(dstp, deg, E);
    int nb = (N + 255) / 256;  // 196 <= 256
    scan1<<<nb, 256, 0, stream>>>(deg, rowptr, bsums, N);
    scan2<<<1, 256, 0, stream>>>(bsums, nb);
    scan3<<<(N + 255) / 256, 256, 0, stream>>>(rowptr, cursor, bsums, N);
    scatter_kernel<<<(Etot + 255) / 256, 256, 0, stream>>>(srcp, dstp, cursor, csrs, E, N);
    aggregate_kernel<<<((size_t)N * 64 + 255) / 256, 256, 0, stream>>>(
        hb, a_src, a_dst, rowptr, csrs, bias, out, N);
}

// Round 3
// 305.754 us; speedup vs baseline: 1.2095x; 1.1251x over previous
//
#include <hip/hip_runtime.h>

#define NEG_SLOPE 0.2f
static constexpr int IN_F = 128;   // input feature dim
static constexpr int NHEAD = 4;
static constexpr int CH = 64;      // channels per head
static constexpr int HC = 256;     // NHEAD*CH

static __host__ size_t align256(size_t v) { return (v + 255) & ~((size_t)255); }

__device__ inline ushort f2bf(float f) {          // round-to-nearest-even fp32->bf16
    unsigned u = __float_as_uint(f);
    unsigned r = u + 0x7FFFu + ((u >> 16) & 1u);
    return (ushort)(r >> 16);
}
__device__ inline float bf2f(ushort s) { return __uint_as_float(((unsigned)s) << 16); }

// ---- GEMM: h[N,256] = x[N,128] @ W[128,256]; fused att dots + bf16 h store --
// grid.y = 4 tiles of 64 cols; each n-tile is exactly one head.
__global__ __launch_bounds__(256) void gemm_att_kernel(
    const float* __restrict__ x, const float* __restrict__ W,
    const float* __restrict__ att_src, const float* __restrict__ att_dst,
    ushort* __restrict__ hb, float* __restrict__ a_src, float* __restrict__ a_dst,
    int N)
{
    __shared__ float As[64][65];   // As[k][r] (transposed), +1 pad vs bank conflicts
    __shared__ float Bs[64][64];   // Bs[k][c]
    const int t = threadIdx.x;
    const int m0 = blockIdx.x * 64;
    const int n0 = blockIdx.y * 64;
    const int head = blockIdx.y;
    const int tc = t & 15;         // col quad 0..15
    const int tr = t >> 4;         // row quad 0..15

    float acc[4][4] = {};

    for (int kt = 0; kt < 2; ++kt) {
        #pragma unroll
        for (int u = 0; u < 4; ++u) {
            int f = t + 256 * u;          // float4 index 0..1023
            int r = f >> 4;               // 0..63
            int k4 = (f & 15) * 4;        // 0..60
            int row = m0 + r;
            float4 v = make_float4(0.f, 0.f, 0.f, 0.f);
            if (row < N)
                v = *(const float4*)(x + (size_t)row * IN_F + kt * 64 + k4);
            As[k4 + 0][r] = v.x;
            As[k4 + 1][r] = v.y;
            As[k4 + 2][r] = v.z;
            As[k4 + 3][r] = v.w;
        }
        #pragma unroll
        for (int u = 0; u < 4; ++u) {
            int f = t + 256 * u;
            int k = f >> 4;               // 0..63
            int c4 = (f & 15) * 4;        // 0..60
            float4 v = *(const float4*)(W + (size_t)(kt * 64 + k) * HC + n0 + c4);
            *(float4*)&Bs[k][c4] = v;
        }
        __syncthreads();
        #pragma unroll 8
        for (int k = 0; k < 64; ++k) {
            float a0 = As[k][4 * tr + 0];
            float a1 = As[k][4 * tr + 1];
            float a2 = As[k][4 * tr + 2];
            float a3 = As[k][4 * tr + 3];
            float4 b = *(const float4*)&Bs[k][4 * tc];
            acc[0][0] += a0 * b.x; acc[0][1] += a0 * b.y; acc[0][2] += a0 * b.z; acc[0][3] += a0 * b.w;
            acc[1][0] += a1 * b.x; acc[1][1] += a1 * b.y; acc[1][2] += a1 * b.z; acc[1][3] += a1 * b.w;
            acc[2][0] += a2 * b.x; acc[2][1] += a2 * b.y; acc[2][2] += a2 * b.z; acc[2][3] += a2 * b.w;
            acc[3][0] += a3 * b.x; acc[3][1] += a3 * b.y; acc[3][2] += a3 * b.z; acc[3][3] += a3 * b.w;
        }
        __syncthreads();
    }

    // epilogue: bf16 h store + per-(row,head) attention dots
    float4 vs = *(const float4*)(att_src + n0 + 4 * tc);
    float4 vd = *(const float4*)(att_dst + n0 + 4 * tc);
    #pragma unroll
    for (int i = 0; i < 4; ++i) {
        int row = m0 + 4 * tr + i;
        float ps = acc[i][0] * vs.x + acc[i][1] * vs.y + acc[i][2] * vs.z + acc[i][3] * vs.w;
        float pd = acc[i][0] * vd.x + acc[i][1] * vd.y + acc[i][2] * vd.z + acc[i][3] * vd.w;
        #pragma unroll
        for (int off = 1; off < 16; off <<= 1) {   // reduce over the 16 tc lanes
            ps += __shfl_xor(ps, off, 64);
            pd += __shfl_xor(pd, off, 64);
        }
        if (row < N) {
            ushort4 o;
            o.x = f2bf(acc[i][0]); o.y = f2bf(acc[i][1]);
            o.z = f2bf(acc[i][2]); o.w = f2bf(acc[i][3]);
            *(ushort4*)(hb + (size_t)row * HC + n0 + 4 * tc) = o;
            if (tc == 0) {
                a_src[(size_t)row * NHEAD + head] = ps;
                a_dst[(size_t)row * NHEAD + head] = pd;
            }
        }
    }
}

// ---------------------------- CSR construction ------------------------------
__global__ void init_deg(int* deg, int* rowptr, int N, int Etot)
{
    int i = blockIdx.x * blockDim.x + threadIdx.x;
    if (i < N) deg[i] = 1;            // self loop
    if (i == 0) rowptr[N] = Etot;
}

__global__ void count_kernel(const int* __restrict__ dst, int* deg, int E)
{
    int e = blockIdx.x * blockDim.x + threadIdx.x;
    if (e < E) atomicAdd(&deg[dst[e]], 1);
}

// block-level exclusive scan, 256 elems/block
__global__ __launch_bounds__(256) void scan1(const int* __restrict__ deg,
                                             int* __restrict__ rowptr,
                                             int* __restrict__ bsums, int N)
{
    __shared__ int sm[256];
    int t = threadIdx.x;
    int i = blockIdx.x * 256 + t;
    int v = (i < N) ? deg[i] : 0;
    sm[t] = v;
    __syncthreads();
    #pragma unroll
    for (int off = 1; off < 256; off <<= 1) {
        int a = sm[t];
        int b = (t >= off) ? sm[t - off] : 0;
        __syncthreads();
        sm[t] = a + b;
        __syncthreads();
    }
    int incl = sm[t];
    if (i < N) rowptr[i] = incl - v;           // block-local exclusive
    if (t == 255) bsums[blockIdx.x] = incl;    // block total
}

__global__ __launch_bounds__(256) void scan2(int* bsums, int nb)
{
    __shared__ int sm[256];
    int t = threadIdx.x;
    int v = (t < nb) ? bsums[t] : 0;
    sm[t] = v;
    __syncthreads();
    #pragma unroll
    for (int off = 1; off < 256; off <<= 1) {
        int a = sm[t];
        int b = (t >= off) ? sm[t - off] : 0;
        __syncthreads();
        sm[t] = a + b;
        __syncthreads();
    }
    if (t < nb) bsums[t] = sm[t] - v;          // exclusive over blocks
}

__global__ void scan3(int* rowptr, int* cursor, const int* __restrict__ bsums, int N)
{
    int i = blockIdx.x * blockDim.x + threadIdx.x;
    if (i < N) {
        int r = rowptr[i] + bsums[i >> 8];
        rowptr[i] = r;
        cursor[i] = r;
    }
}

__global__ void scatter_kernel(const int* __restrict__ src, const int* __restrict__ dst,
                               int* cursor, int* __restrict__ csr_src, int E, int N)
{
    int t = blockIdx.x * blockDim.x + threadIdx.x;
    if (t < E) {
        int d = dst[t];
        int pos = atomicAdd(&cursor[d], 1);
        csr_src[pos] = src[t];
    } else if (t < E + N) {
        int d = t - E;                          // self loop
        int pos = atomicAdd(&cursor[d], 1);
        csr_src[pos] = d;
    }
}

// ------------- single-pass softmax aggregate (no max subtraction) -----------
// Logits e = leaky_relu(a_src+a_dst) are O(±10): exp() cannot overflow fp32,
// so accumulate acc += exp(e)*h and s += exp(e) in ONE edge sweep, divide at
// the end. One wave per node; lane l: head l>>4, channels 4*(l&15)..+3.
// 2-edge unroll with independent accumulators for memory-level parallelism.
__global__ __launch_bounds__(256) void aggregate_kernel(
    const ushort* __restrict__ hb, const float* __restrict__ a_src,
    const float* __restrict__ a_dst, const int* __restrict__ rowptr,
    const int* __restrict__ csr_src, const float* __restrict__ bias,
    float* __restrict__ out, int N)
{
    int node = (int)((blockIdx.x * (size_t)blockDim.x + threadIdx.x) >> 6);
    int l = threadIdx.x & 63;
    if (node >= N) return;
    int start = rowptr[node];
    int end = rowptr[node + 1];
    int hd = l >> 4;
    float adh = a_dst[(size_t)node * NHEAD + hd];

    float4 acc0 = make_float4(0.f, 0.f, 0.f, 0.f);
    float4 acc1 = make_float4(0.f, 0.f, 0.f, 0.f);
    float s0 = 0.f, s1 = 0.f;

    int k = start;
    for (; k + 2 <= end; k += 2) {
        int sj0 = csr_src[k];
        int sj1 = csr_src[k + 1];
        float a0 = a_src[(size_t)sj0 * NHEAD + hd];
        float a1 = a_src[(size_t)sj1 * NHEAD + hd];
        ushort4 h0 = *(const ushort4*)(hb + ((size_t)sj0 << 8) + 4 * l);
        ushort4 h1 = *(const ushort4*)(hb + ((size_t)sj1 << 8) + 4 * l);
        float e0 = a0 + adh; e0 = fmaxf(e0, NEG_SLOPE * e0);
        float e1 = a1 + adh; e1 = fmaxf(e1, NEG_SLOPE * e1);
        float w0 = __expf(e0);
        float w1 = __expf(e1);
        s0 += w0; s1 += w1;
        acc0.x += w0 * bf2f(h0.x); acc0.y += w0 * bf2f(h0.y);
        acc0.z += w0 * bf2f(h0.z); acc0.w += w0 * bf2f(h0.w);
        acc1.x += w1 * bf2f(h1.x); acc1.y += w1 * bf2f(h1.y);
        acc1.z += w1 * bf2f(h1.z); acc1.w += w1 * bf2f(h1.w);
    }
    if (k < end) {                               // tail edge
        int sj0 = csr_src[k];
        float a0 = a_src[(size_t)sj0 * NHEAD + hd];
        ushort4 h0 = *(const ushort4*)(hb + ((size_t)sj0 << 8) + 4 * l);
        float e0 = a0 + adh; e0 = fmaxf(e0, NEG_SLOPE * e0);
        float w0 = __expf(e0);
        s0 += w0;
        acc0.x += w0 * bf2f(h0.x); acc0.y += w0 * bf2f(h0.y);
        acc0.z += w0 * bf2f(h0.z); acc0.w += w0 * bf2f(h0.w);
    }

    float inv = 1.0f / (s0 + s1);               // per-head softmax denominator
    float4 acc;
    acc.x = (acc0.x + acc1.x) * inv;
    acc.y = (acc0.y + acc1.y) * inv;
    acc.z = (acc0.z + acc1.z) * inv;
    acc.w = (acc0.w + acc1.w) * inv;

    // reduce over heads: lanes l, l^16, l^32, l^48 hold same channels
    #pragma unroll
    for (int off = 16; off < 64; off <<= 1) {
        acc.x += __shfl_xor(acc.x, off, 64);
        acc.y += __shfl_xor(acc.y, off, 64);
        acc.z += __shfl_xor(acc.z, off, 64);
        acc.w += __shfl_xor(acc.w, off, 64);
    }
    if (l < 16) {
        float4 b4 = *(const float4*)(bias + 4 * l);
        float4 o;
        o.x = acc.x * 0.25f + b4.x;
        o.y = acc.y * 0.25f + b4.y;
        o.z = acc.z * 0.25f + b4.z;
        o.w = acc.w * 0.25f + b4.w;
        o.x = (o.x > 0.f) ? o.x : (__expf(o.x) - 1.f);
        o.y = (o.y > 0.f) ? o.y : (__expf(o.y) - 1.f);
        o.z = (o.z > 0.f) ? o.z : (__expf(o.z) - 1.f);
        o.w = (o.w > 0.f) ? o.w : (__expf(o.w) - 1.f);
        *(float4*)(out + (size_t)node * CH + 4 * l) = o;
    }
}

extern "C" void kernel_launch(void* const* d_in, const int* in_sizes, int n_in,
                              void* d_out, int out_size, void* d_ws, size_t ws_size,
                              hipStream_t stream)
{
    const float* x         = (const float*)d_in[0];
    const int*   edge_idx  = (const int*)d_in[1];
    const float* W         = (const float*)d_in[2];
    const float* att_src   = (const float*)d_in[3];
    const float* att_dst   = (const float*)d_in[4];
    const float* bias      = (const float*)d_in[5];
    float* out = (float*)d_out;

    const int N = in_sizes[0] / IN_F;
    const int E = in_sizes[1] / 2;
    const int Etot = E + N;
    const int* srcp = edge_idx;
    const int* dstp = edge_idx + E;

    char* ws = (char*)d_ws;
    size_t off = 0;
    ushort* hb    = (ushort*)(ws + off); off += align256((size_t)N * HC * sizeof(ushort));
    float* a_src  = (float*)(ws + off);  off += align256((size_t)N * NHEAD * sizeof(float));
    float* a_dst  = (float*)(ws + off);  off += align256((size_t)N * NHEAD * sizeof(float));
    int*   deg    = (int*)(ws + off);    off += align256((size_t)N * sizeof(int));
    int*   rowptr = (int*)(ws + off);    off += align256(((size_t)N + 1) * sizeof(int));
    int*   cursor = (int*)(ws + off);    off += align256((size_t)N * sizeof(int));
    int*   csrs   = (int*)(ws + off);    off += align256((size_t)Etot * sizeof(int));
    int*   bsums  = (int*)(ws + off);    off += align256(256 * sizeof(int));
    (void)ws_size; (void)n_in; (void)out_size;

    dim3 gg((N + 63) / 64, HC / 64);
    gemm_att_kernel<<<gg, 256, 0, stream>>>(x, W, att_src, att_dst, hb, a_src, a_dst, N);
    init_deg<<<(N + 255) / 256, 256, 0, stream>>>(deg, rowptr, N, Etot);
    count_kernel<<<(E + 255) / 256, 256, 0, stream>>>(dstp, deg, E);
    int nb = (N + 255) / 256;  // 196 <= 256
    scan1<<<nb, 256, 0, stream>>>(deg, rowptr, bsums, N);
    scan2<<<1, 256, 0, stream>>>(bsums, nb);
    scan3<<<(N + 255) / 256, 256, 0, stream>>>(rowptr, cursor, bsums, N);
    scatter_kernel<<<(Etot + 255) / 256, 256, 0, stream>>>(srcp, dstp, cursor, csrs, E, N);
    aggregate_kernel<<<((size_t)N * 64 + 255) / 256, 256, 0, stream>>>(
        hb, a_src, a_dst, rowptr, csrs, bias, out, N);
}

// Round 4
// 268.550 us; speedup vs baseline: 1.3771x; 1.1385x over previous
//
#include <hip/hip_runtime.h>

#define NEG_SLOPE 0.2f
static constexpr int IN_F = 128;   // input feature dim
static constexpr int NHEAD = 4;
static constexpr int CH = 64;      // channels per head
static constexpr int HC = 256;     // NHEAD*CH

static __host__ size_t align256(size_t v) { return (v + 255) & ~((size_t)255); }

__device__ inline ushort f2bf(float f) {          // round-to-nearest-even fp32->bf16
    unsigned u = __float_as_uint(f);
    unsigned r = u + 0x7FFFu + ((u >> 16) & 1u);
    return (ushort)(r >> 16);
}
__device__ inline float bf2f(ushort s) { return __uint_as_float(((unsigned)s) << 16); }

typedef short s16x8 __attribute__((ext_vector_type(8)));    // 8 bf16 = 4 VGPR
typedef float f32x16 __attribute__((ext_vector_type(16)));  // 32x32 accumulator

// ---- MFMA GEMM: h[N,256] = bf16(x)[N,128] @ bf16(W)[128,256] ---------------
// grid (ceil(N/64), 4 heads). Block: 64 rows x 64 cols (one head), K=128.
// 4 waves; wave w owns the 32x32 quadrant (row-half w>>1, col-half w&1).
// Epilogue: acc -> LDS h-tile (bf16) -> coalesced global store + fused
// att_src/att_dst dot products.
__global__ __launch_bounds__(256) void gemm_mfma_kernel(
    const float* __restrict__ x, const float* __restrict__ W,
    const float* __restrict__ att_src, const float* __restrict__ att_dst,
    ushort* __restrict__ hb, float* __restrict__ a_src, float* __restrict__ a_dst,
    int N)
{
    constexpr int LDK = 136;            // padded K stride (bf16 elems)
    constexpr int HS  = 72;             // padded h-tile stride
    __shared__ ushort As[64 * LDK];     // A[m][k] bf16
    __shared__ ushort Bs[64 * LDK];     // B^T[n][k] bf16
    ushort* Hs = As;                    // h-tile aliases As after MFMA

    const int t = threadIdx.x;
    const int m0 = blockIdx.x * 64;
    const int head = blockIdx.y;
    const int n0 = head * 64;

    // stage A: x tile 64x128 fp32 -> bf16 (coalesced float4 loads)
    #pragma unroll
    for (int u = 0; u < 8; ++u) {
        int f = t + 256 * u;            // 2048 float4s
        int r = f >> 5;                 // row 0..63
        int c4 = (f & 31) * 4;          // k 0..124
        int row = m0 + r;
        float4 v = make_float4(0.f, 0.f, 0.f, 0.f);
        if (row < N) v = *(const float4*)(x + (size_t)row * IN_F + c4);
        ushort4 o;
        o.x = f2bf(v.x); o.y = f2bf(v.y); o.z = f2bf(v.z); o.w = f2bf(v.w);
        *(ushort4*)&As[r * LDK + c4] = o;
    }
    // stage B^T: W[k][n0+n] -> Bs[n][k] (coalesced float4 loads, scattered LDS)
    #pragma unroll
    for (int u = 0; u < 8; ++u) {
        int f = t + 256 * u;            // 2048 float4s: 128 k x 16 n-quads
        int k = f >> 4;                 // 0..127
        int n4 = (f & 15) * 4;
        float4 v = *(const float4*)(W + (size_t)k * HC + n0 + n4);
        Bs[(n4 + 0) * LDK + k] = f2bf(v.x);
        Bs[(n4 + 1) * LDK + k] = f2bf(v.y);
        Bs[(n4 + 2) * LDK + k] = f2bf(v.z);
        Bs[(n4 + 3) * LDK + k] = f2bf(v.w);
    }
    __syncthreads();

    const int w = t >> 6;
    const int lane = t & 63;
    const int mbase = 32 * (w >> 1) + (lane & 31);
    const int nbase = 32 * (w & 1) + (lane & 31);
    const int kq = (lane >> 5) * 8;     // 0 or 8

    f32x16 acc = {};
    #pragma unroll
    for (int s = 0; s < 8; ++s) {       // K = 8 x 16
        s16x8 af = *(const s16x8*)&As[mbase * LDK + 16 * s + kq];
        s16x8 bf = *(const s16x8*)&Bs[nbase * LDK + 16 * s + kq];
        acc = __builtin_amdgcn_mfma_f32_32x32x16_bf16(af, bf, acc, 0, 0, 0);
    }
    __syncthreads();                    // done reading As/Bs; Hs aliases As

    // acc -> LDS h tile (bf16). C layout: col=lane&31, row=(r&3)+8*(r>>2)+4*(lane>>5)
    {
        int colL = (lane & 31) + 32 * (w & 1);
        int rbase = 4 * (lane >> 5) + 32 * (w >> 1);
        #pragma unroll
        for (int r = 0; r < 16; ++r) {
            int rowL = rbase + (r & 3) + 8 * (r >> 2);
            Hs[rowL * HS + colL] = f2bf(acc[r]);
        }
    }
    __syncthreads();

    // coalesced h store + fused att dots. thread t: row t>>2, col quarter t&3
    {
        int r2 = t >> 2;
        int q = t & 3;
        int row = m0 + r2;
        uint4 p0 = *(const uint4*)&Hs[r2 * HS + 16 * q];
        uint4 p1 = *(const uint4*)&Hs[r2 * HS + 16 * q + 8];
        if (row < N) {
            *(uint4*)(hb + (size_t)row * HC + n0 + 16 * q) = p0;
            *(uint4*)(hb + (size_t)row * HC + n0 + 16 * q + 8) = p1;
        }
        const float* asp = att_src + n0 + 16 * q;
        const float* adp = att_dst + n0 + 16 * q;
        unsigned uu[8] = { p0.x, p0.y, p0.z, p0.w, p1.x, p1.y, p1.z, p1.w };
        float ps = 0.f, pd = 0.f;
        #pragma unroll
        for (int i = 0; i < 8; ++i) {
            float lo = bf2f((ushort)(uu[i] & 0xFFFFu));
            float hi = bf2f((ushort)(uu[i] >> 16));
            ps += lo * asp[2 * i] + hi * asp[2 * i + 1];
            pd += lo * adp[2 * i] + hi * adp[2 * i + 1];
        }
        ps += __shfl_xor(ps, 1, 64); ps += __shfl_xor(ps, 2, 64);
        pd += __shfl_xor(pd, 1, 64); pd += __shfl_xor(pd, 2, 64);
        if (q == 0 && row < N) {
            a_src[(size_t)row * NHEAD + head] = ps;
            a_dst[(size_t)row * NHEAD + head] = pd;
        }
    }
}

// ---------------------------- CSR construction ------------------------------
__global__ void count_kernel(const int* __restrict__ dst, int* deg, int E)
{
    int e = blockIdx.x * blockDim.x + threadIdx.x;
    if (e < E) atomicAdd(&deg[dst[e]], 1);
}

// block-level exclusive scan, 256 elems/block; +1 per node = self loop
__global__ __launch_bounds__(256) void scan1(const int* __restrict__ deg,
                                             int* __restrict__ rowptr,
                                             int* __restrict__ bsums, int N)
{
    __shared__ int sm[256];
    int t = threadIdx.x;
    int i = blockIdx.x * 256 + t;
    int v = (i < N) ? (deg[i] + 1) : 0;
    sm[t] = v;
    __syncthreads();
    #pragma unroll
    for (int off = 1; off < 256; off <<= 1) {
        int a = sm[t];
        int b = (t >= off) ? sm[t - off] : 0;
        __syncthreads();
        sm[t] = a + b;
        __syncthreads();
    }
    int incl = sm[t];
    if (i < N) rowptr[i] = incl - v;           // block-local exclusive
    if (t == 255) bsums[blockIdx.x] = incl;    // block total
}

__global__ __launch_bounds__(256) void scan2(int* bsums, int nb)
{
    __shared__ int sm[256];
    int t = threadIdx.x;
    int v = (t < nb) ? bsums[t] : 0;
    sm[t] = v;
    __syncthreads();
    #pragma unroll
    for (int off = 1; off < 256; off <<= 1) {
        int a = sm[t];
        int b = (t >= off) ? sm[t - off] : 0;
        __syncthreads();
        sm[t] = a + b;
        __syncthreads();
    }
    if (t < nb) bsums[t] = sm[t] - v;          // exclusive over blocks
}

__global__ void scan3(int* rowptr, int* cursor, const int* __restrict__ bsums,
                      int N, int Etot)
{
    int i = blockIdx.x * blockDim.x + threadIdx.x;
    if (i < N) {
        int r = rowptr[i] + bsums[i >> 8];
        rowptr[i] = r;
        cursor[i] = r;
    }
    if (i == 0) rowptr[N] = Etot;
}

__global__ void scatter_kernel(const int* __restrict__ src, const int* __restrict__ dst,
                               int* cursor, int* __restrict__ csr_src, int E, int N)
{
    int t = blockIdx.x * blockDim.x + threadIdx.x;
    if (t < E) {
        int d = dst[t];
        int pos = atomicAdd(&cursor[d], 1);
        csr_src[pos] = src[t];
    } else if (t < E + N) {
        int d = t - E;                          // self loop
        int pos = atomicAdd(&cursor[d], 1);
        csr_src[pos] = d;
    }
}

// ------------- single-pass softmax aggregate (no max subtraction) -----------
// Logits e = leaky_relu(a_src+a_dst) are O(±10): exp() cannot overflow fp32.
// One wave per node; lane l: head l>>4, channels 4*(l&15)..+3.
// 4-edge unroll, independent accumulators for memory-level parallelism.
__global__ __launch_bounds__(256) void aggregate_kernel(
    const ushort* __restrict__ hb, const float* __restrict__ a_src,
    const float* __restrict__ a_dst, const int* __restrict__ rowptr,
    const int* __restrict__ csr_src, const float* __restrict__ bias,
    float* __restrict__ out, int N)
{
    int node = (int)((blockIdx.x * (size_t)blockDim.x + threadIdx.x) >> 6);
    int l = threadIdx.x & 63;
    if (node >= N) return;
    int start = rowptr[node];
    int end = rowptr[node + 1];
    int hd = l >> 4;
    float adh = a_dst[(size_t)node * NHEAD + hd];

    float4 acc0 = make_float4(0.f, 0.f, 0.f, 0.f);
    float4 acc1 = make_float4(0.f, 0.f, 0.f, 0.f);
    float4 acc2 = make_float4(0.f, 0.f, 0.f, 0.f);
    float4 acc3 = make_float4(0.f, 0.f, 0.f, 0.f);
    float s0 = 0.f, s1 = 0.f, s2 = 0.f, s3 = 0.f;

    int k = start;
    for (; k + 4 <= end; k += 4) {
        int sj0 = csr_src[k];
        int sj1 = csr_src[k + 1];
        int sj2 = csr_src[k + 2];
        int sj3 = csr_src[k + 3];
        float a0 = a_src[(size_t)sj0 * NHEAD + hd];
        float a1 = a_src[(size_t)sj1 * NHEAD + hd];
        float a2 = a_src[(size_t)sj2 * NHEAD + hd];
        float a3 = a_src[(size_t)sj3 * NHEAD + hd];
        ushort4 h0 = *(const ushort4*)(hb + ((size_t)sj0 << 8) + 4 * l);
        ushort4 h1 = *(const ushort4*)(hb + ((size_t)sj1 << 8) + 4 * l);
        ushort4 h2 = *(const ushort4*)(hb + ((size_t)sj2 << 8) + 4 * l);
        ushort4 h3 = *(const ushort4*)(hb + ((size_t)sj3 << 8) + 4 * l);
        float e0 = a0 + adh; e0 = fmaxf(e0, NEG_SLOPE * e0); float w0 = __expf(e0);
        float e1 = a1 + adh; e1 = fmaxf(e1, NEG_SLOPE * e1); float w1 = __expf(e1);
        float e2 = a2 + adh; e2 = fmaxf(e2, NEG_SLOPE * e2); float w2 = __expf(e2);
        float e3 = a3 + adh; e3 = fmaxf(e3, NEG_SLOPE * e3); float w3 = __expf(e3);
        s0 += w0; s1 += w1; s2 += w2; s3 += w3;
        acc0.x += w0 * bf2f(h0.x); acc0.y += w0 * bf2f(h0.y);
        acc0.z += w0 * bf2f(h0.z); acc0.w += w0 * bf2f(h0.w);
        acc1.x += w1 * bf2f(h1.x); acc1.y += w1 * bf2f(h1.y);
        acc1.z += w1 * bf2f(h1.z); acc1.w += w1 * bf2f(h1.w);
        acc2.x += w2 * bf2f(h2.x); acc2.y += w2 * bf2f(h2.y);
        acc2.z += w2 * bf2f(h2.z); acc2.w += w2 * bf2f(h2.w);
        acc3.x += w3 * bf2f(h3.x); acc3.y += w3 * bf2f(h3.y);
        acc3.z += w3 * bf2f(h3.z); acc3.w += w3 * bf2f(h3.w);
    }
    for (; k < end; ++k) {                       // tail (<=3 edges)
        int sj0 = csr_src[k];
        float a0 = a_src[(size_t)sj0 * NHEAD + hd];
        ushort4 h0 = *(const ushort4*)(hb + ((size_t)sj0 << 8) + 4 * l);
        float e0 = a0 + adh; e0 = fmaxf(e0, NEG_SLOPE * e0);
        float w0 = __expf(e0);
        s0 += w0;
        acc0.x += w0 * bf2f(h0.x); acc0.y += w0 * bf2f(h0.y);
        acc0.z += w0 * bf2f(h0.z); acc0.w += w0 * bf2f(h0.w);
    }

    float inv = 1.0f / (s0 + s1 + s2 + s3);      // per-head softmax denominator
    float4 acc;
    acc.x = (acc0.x + acc1.x + acc2.x + acc3.x) * inv;
    acc.y = (acc0.y + acc1.y + acc2.y + acc3.y) * inv;
    acc.z = (acc0.z + acc1.z + acc2.z + acc3.z) * inv;
    acc.w = (acc0.w + acc1.w + acc2.w + acc3.w) * inv;

    // reduce over heads: lanes l, l^16, l^32, l^48 hold same channels
    #pragma unroll
    for (int off = 16; off < 64; off <<= 1) {
        acc.x += __shfl_xor(acc.x, off, 64);
        acc.y += __shfl_xor(acc.y, off, 64);
        acc.z += __shfl_xor(acc.z, off, 64);
        acc.w += __shfl_xor(acc.w, off, 64);
    }
    if (l < 16) {
        float4 b4 = *(const float4*)(bias + 4 * l);
        float4 o;
        o.x = acc.x * 0.25f + b4.x;
        o.y = acc.y * 0.25f + b4.y;
        o.z = acc.z * 0.25f + b4.z;
        o.w = acc.w * 0.25f + b4.w;
        o.x = (o.x > 0.f) ? o.x : (__expf(o.x) - 1.f);
        o.y = (o.y > 0.f) ? o.y : (__expf(o.y) - 1.f);
        o.z = (o.z > 0.f) ? o.z : (__expf(o.z) - 1.f);
        o.w = (o.w > 0.f) ? o.w : (__expf(o.w) - 1.f);
        *(float4*)(out + (size_t)node * CH + 4 * l) = o;
    }
}

extern "C" void kernel_launch(void* const* d_in, const int* in_sizes, int n_in,
                              void* d_out, int out_size, void* d_ws, size_t ws_size,
                              hipStream_t stream)
{
    const float* x         = (const float*)d_in[0];
    const int*   edge_idx  = (const int*)d_in[1];
    const float* W         = (const float*)d_in[2];
    const float* att_src   = (const float*)d_in[3];
    const float* att_dst   = (const float*)d_in[4];
    const float* bias      = (const float*)d_in[5];
    float* out = (float*)d_out;

    const int N = in_sizes[0] / IN_F;
    const int E = in_sizes[1] / 2;
    const int Etot = E + N;
    const int* srcp = edge_idx;
    const int* dstp = edge_idx + E;

    char* ws = (char*)d_ws;
    size_t off = 0;
    ushort* hb    = (ushort*)(ws + off); off += align256((size_t)N * HC * sizeof(ushort));
    float* a_src  = (float*)(ws + off);  off += align256((size_t)N * NHEAD * sizeof(float));
    float* a_dst  = (float*)(ws + off);  off += align256((size_t)N * NHEAD * sizeof(float));
    int*   deg    = (int*)(ws + off);    off += align256((size_t)N * sizeof(int));
    int*   rowptr = (int*)(ws + off);    off += align256(((size_t)N + 1) * sizeof(int));
    int*   cursor = (int*)(ws + off);    off += align256((size_t)N * sizeof(int));
    int*   csrs   = (int*)(ws + off);    off += align256((size_t)Etot * sizeof(int));
    int*   bsums  = (int*)(ws + off);    off += align256(256 * sizeof(int));
    (void)ws_size; (void)n_in; (void)out_size;

    dim3 gg((N + 63) / 64, NHEAD);
    gemm_mfma_kernel<<<gg, 256, 0, stream>>>(x, W, att_src, att_dst, hb, a_src, a_dst, N);
    hipMemsetAsync(deg, 0, (size_t)N * sizeof(int), stream);
    count_kernel<<<(E + 255) / 256, 256, 0, stream>>>(dstp, deg, E);
    int nb = (N + 255) / 256;  // 196 <= 256
    scan1<<<nb, 256, 0, stream>>>(deg, rowptr, bsums, N);
    scan2<<<1, 256, 0, stream>>>(bsums, nb);
    scan3<<<(N + 255) / 256, 256, 0, stream>>>(rowptr, cursor, bsums, N, Etot);
    scatter_kernel<<<(Etot + 255) / 256, 256, 0, stream>>>(srcp, dstp, cursor, csrs, E, N);
    aggregate_kernel<<<((size_t)N * 64 + 255) / 256, 256, 0, stream>>>(
        hb, a_src, a_dst, rowptr, csrs, bias, out, N);
}

// Round 5
// 214.144 us; speedup vs baseline: 1.7270x; 1.2541x over previous
//
#include <hip/hip_runtime.h>

#define NEG_SLOPE 0.2f
static constexpr int IN_F = 128;   // input feature dim
static constexpr int NHEAD = 4;
static constexpr int CH = 64;      // channels per head
static constexpr int HC = 256;     // NHEAD*CH

static __host__ size_t align256(size_t v) { return (v + 255) & ~((size_t)255); }

__device__ inline ushort f2bf(float f) {          // round-to-nearest-even fp32->bf16
    unsigned u = __float_as_uint(f);
    unsigned r = u + 0x7FFFu + ((u >> 16) & 1u);
    return (ushort)(r >> 16);
}
__device__ inline float bf2f(ushort s) { return __uint_as_float(((unsigned)s) << 16); }

typedef short s16x8 __attribute__((ext_vector_type(8)));    // 8 bf16 = 4 VGPR
typedef float f32x16 __attribute__((ext_vector_type(16)));  // 32x32 accumulator

// ---- MFMA GEMM: h[N,256] = bf16(x)[N,128] @ bf16(W)[128,256] ---------------
// grid (ceil(N/64), 4 heads). Block (0,0) also zeroes coarse_cnt (stream order
// guarantees visibility to bucket_count which runs after this kernel).
__global__ __launch_bounds__(256) void gemm_mfma_kernel(
    const float* __restrict__ x, const float* __restrict__ W,
    const float* __restrict__ att_src, const float* __restrict__ att_dst,
    ushort* __restrict__ hb, float* __restrict__ a_src, float* __restrict__ a_dst,
    int* __restrict__ coarse_cnt, int NB, int N)
{
    constexpr int LDK = 136;            // padded K stride (bf16 elems)
    constexpr int HS  = 72;             // padded h-tile stride
    __shared__ ushort As[64 * LDK];     // A[m][k] bf16
    __shared__ ushort Bs[64 * LDK];     // B^T[n][k] bf16
    ushort* Hs = As;                    // h-tile aliases As after MFMA

    const int t = threadIdx.x;
    const int m0 = blockIdx.x * 64;
    const int head = blockIdx.y;
    const int n0 = head * 64;

    if (blockIdx.x == 0 && blockIdx.y == 0 && t < NB) coarse_cnt[t] = 0;

    // stage A: x tile 64x128 fp32 -> bf16 (coalesced float4 loads)
    #pragma unroll
    for (int u = 0; u < 8; ++u) {
        int f = t + 256 * u;            // 2048 float4s
        int r = f >> 5;                 // row 0..63
        int c4 = (f & 31) * 4;          // k 0..124
        int row = m0 + r;
        float4 v = make_float4(0.f, 0.f, 0.f, 0.f);
        if (row < N) v = *(const float4*)(x + (size_t)row * IN_F + c4);
        ushort4 o;
        o.x = f2bf(v.x); o.y = f2bf(v.y); o.z = f2bf(v.z); o.w = f2bf(v.w);
        *(ushort4*)&As[r * LDK + c4] = o;
    }
    // stage B^T: W[k][n0+n] -> Bs[n][k] (coalesced float4 loads, scattered LDS)
    #pragma unroll
    for (int u = 0; u < 8; ++u) {
        int f = t + 256 * u;            // 2048 float4s: 128 k x 16 n-quads
        int k = f >> 4;                 // 0..127
        int n4 = (f & 15) * 4;
        float4 v = *(const float4*)(W + (size_t)k * HC + n0 + n4);
        Bs[(n4 + 0) * LDK + k] = f2bf(v.x);
        Bs[(n4 + 1) * LDK + k] = f2bf(v.y);
        Bs[(n4 + 2) * LDK + k] = f2bf(v.z);
        Bs[(n4 + 3) * LDK + k] = f2bf(v.w);
    }
    __syncthreads();

    const int w = t >> 6;
    const int lane = t & 63;
    const int mbase = 32 * (w >> 1) + (lane & 31);
    const int nbase = 32 * (w & 1) + (lane & 31);
    const int kq = (lane >> 5) * 8;     // 0 or 8

    f32x16 acc = {};
    #pragma unroll
    for (int s = 0; s < 8; ++s) {       // K = 8 x 16
        s16x8 af = *(const s16x8*)&As[mbase * LDK + 16 * s + kq];
        s16x8 bf = *(const s16x8*)&Bs[nbase * LDK + 16 * s + kq];
        acc = __builtin_amdgcn_mfma_f32_32x32x16_bf16(af, bf, acc, 0, 0, 0);
    }
    __syncthreads();                    // done reading As/Bs; Hs aliases As

    // acc -> LDS h tile (bf16). C layout: col=lane&31, row=(r&3)+8*(r>>2)+4*(lane>>5)
    {
        int colL = (lane & 31) + 32 * (w & 1);
        int rbase = 4 * (lane >> 5) + 32 * (w >> 1);
        #pragma unroll
        for (int r = 0; r < 16; ++r) {
            int rowL = rbase + (r & 3) + 8 * (r >> 2);
            Hs[rowL * HS + colL] = f2bf(acc[r]);
        }
    }
    __syncthreads();

    // coalesced h store + fused att dots. thread t: row t>>2, col quarter t&3
    {
        int r2 = t >> 2;
        int q = t & 3;
        int row = m0 + r2;
        uint4 p0 = *(const uint4*)&Hs[r2 * HS + 16 * q];
        uint4 p1 = *(const uint4*)&Hs[r2 * HS + 16 * q + 8];
        if (row < N) {
            *(uint4*)(hb + (size_t)row * HC + n0 + 16 * q) = p0;
            *(uint4*)(hb + (size_t)row * HC + n0 + 16 * q + 8) = p1;
        }
        const float* asp = att_src + n0 + 16 * q;
        const float* adp = att_dst + n0 + 16 * q;
        unsigned uu[8] = { p0.x, p0.y, p0.z, p0.w, p1.x, p1.y, p1.z, p1.w };
        float ps = 0.f, pd = 0.f;
        #pragma unroll
        for (int i = 0; i < 8; ++i) {
            float lo = bf2f((ushort)(uu[i] & 0xFFFFu));
            float hi = bf2f((ushort)(uu[i] >> 16));
            ps += lo * asp[2 * i] + hi * asp[2 * i + 1];
            pd += lo * adp[2 * i] + hi * adp[2 * i + 1];
        }
        ps += __shfl_xor(ps, 1, 64); ps += __shfl_xor(ps, 2, 64);
        pd += __shfl_xor(pd, 1, 64); pd += __shfl_xor(pd, 2, 64);
        if (q == 0 && row < N) {
            a_src[(size_t)row * NHEAD + head] = ps;
            a_dst[(size_t)row * NHEAD + head] = pd;
        }
    }
}

// --------------- CSR build via coarse bucketing (no per-edge atomics) -------
// Bucket b = dst >> 8 (NB = ceil(N/256) <= 256 buckets).

// pass 1: coarse histogram. One LDS hist per block, one global atomic per
// (block, nonempty bucket).
__global__ __launch_bounds__(256) void bucket_count(
    const int* __restrict__ dst, int* __restrict__ coarse_cnt,
    int E, int epb, int NB)
{
    __shared__ int hist[256];
    int t = threadIdx.x;
    hist[t] = 0;
    __syncthreads();
    int lo = blockIdx.x * epb;
    int hi = min(E, lo + epb);
    for (int i = lo + t; i < hi; i += 256)
        atomicAdd(&hist[((unsigned)dst[i]) >> 8], 1);
    __syncthreads();
    if (t < NB && hist[t]) atomicAdd(&coarse_cnt[t], hist[t]);
}

// pass 2: scan of coarse counts (NB <= 256, one block)
__global__ __launch_bounds__(256) void scan_coarse(
    const int* __restrict__ coarse_cnt, int* __restrict__ ebase,
    int* __restrict__ bucket_cur, int* __restrict__ rowptr,
    int NB, int N, int E)
{
    __shared__ int sm[256];
    int t = threadIdx.x;
    int v = (t < NB) ? coarse_cnt[t] : 0;
    sm[t] = v;
    __syncthreads();
    #pragma unroll
    for (int off = 1; off < 256; off <<= 1) {
        int a = sm[t];
        int b = (t >= off) ? sm[t - off] : 0;
        __syncthreads();
        sm[t] = a + b;
        __syncthreads();
    }
    int incl = sm[t];
    int excl = incl - v;
    if (t < NB) { ebase[t] = excl; bucket_cur[t] = excl; }
    if (t == NB - 1) ebase[NB] = incl;
    if (t == 0) rowptr[N] = E + N;
}

// pass 3: scatter edges into bucket regions. Per-block LDS histogram ->
// one reservation atomic per (block,bucket) -> LDS-atomic local offsets.
// Packed value: (src << 8) | (dst & 255)   (src < 65536, fits)
__global__ __launch_bounds__(256) void bucket_scatter(
    const int* __restrict__ src, const int* __restrict__ dst,
    int* __restrict__ bucket_cur, unsigned* __restrict__ ebuf,
    int E, int epb, int NB)
{
    __shared__ int hist[256];
    __shared__ int base[256];
    int t = threadIdx.x;
    hist[t] = 0;
    __syncthreads();
    int lo = blockIdx.x * epb;
    int hi = min(E, lo + epb);
    for (int i = lo + t; i < hi; i += 256)
        atomicAdd(&hist[((unsigned)dst[i]) >> 8], 1);
    __syncthreads();
    if (t < NB && hist[t]) base[t] = atomicAdd(&bucket_cur[t], hist[t]);
    __syncthreads();
    hist[t] = 0;                        // reuse as local offset cursor
    __syncthreads();
    for (int i = lo + t; i < hi; i += 256) {
        unsigned d = (unsigned)dst[i];
        unsigned b = d >> 8;
        int off2 = atomicAdd(&hist[b], 1);
        ebuf[base[b] + off2] = (((unsigned)src[i]) << 8) | (d & 255u);
    }
}

// pass 4: per-bucket CSR finalize. One block per bucket; 256-bin LDS
// histogram + scan + LDS-cursor scatter. Self loop goes first in each segment.
__global__ __launch_bounds__(256) void csr_build(
    const unsigned* __restrict__ ebuf, const int* __restrict__ ebase,
    int* __restrict__ rowptr, int* __restrict__ csr_src, int N)
{
    __shared__ int hist[256];
    __shared__ int scn[256];
    __shared__ int cur[256];
    int b = blockIdx.x;
    int t = threadIdx.x;
    int n0 = b << 8;
    int ncnt = min(256, N - n0);
    int lo = ebase[b], hi = ebase[b + 1];
    int cb = lo + n0;                   // global csr base (n0 = self loops before)
    hist[t] = 0;
    __syncthreads();
    for (int i = lo + t; i < hi; i += 256)
        atomicAdd(&hist[ebuf[i] & 255u], 1);
    __syncthreads();
    int v = hist[t];
    scn[t] = v;
    __syncthreads();
    #pragma unroll
    for (int off = 1; off < 256; off <<= 1) {
        int a = scn[t];
        int bb = (t >= off) ? scn[t - off] : 0;
        __syncthreads();
        scn[t] = a + bb;
        __syncthreads();
    }
    int excl = scn[t] - v;
    int segstart = cb + excl + t;       // +t = self loops of prior nodes
    if (t < ncnt) {
        rowptr[n0 + t] = segstart;
        csr_src[segstart] = n0 + t;     // self loop first
    }
    cur[t] = excl + t + 1;              // local cursor, skip self slot
    __syncthreads();
    for (int i = lo + t; i < hi; i += 256) {
        unsigned e = ebuf[i];
        int ln = (int)(e & 255u);
        int pos = atomicAdd(&cur[ln], 1);
        csr_src[cb + pos] = (int)(e >> 8);
    }
}

// ------------- single-pass softmax aggregate (no max subtraction) -----------
// Logits e = leaky_relu(a_src+a_dst) are O(±10): exp() cannot overflow fp32.
// One wave per node; lane l: head l>>4, channels 4*(l&15)..+3.
// 4-edge unroll, independent accumulators for memory-level parallelism.
__global__ __launch_bounds__(256) void aggregate_kernel(
    const ushort* __restrict__ hb, const float* __restrict__ a_src,
    const float* __restrict__ a_dst, const int* __restrict__ rowptr,
    const int* __restrict__ csr_src, const float* __restrict__ bias,
    float* __restrict__ out, int N)
{
    int node = (int)((blockIdx.x * (size_t)blockDim.x + threadIdx.x) >> 6);
    int l = threadIdx.x & 63;
    if (node >= N) return;
    int start = rowptr[node];
    int end = rowptr[node + 1];
    int hd = l >> 4;
    float adh = a_dst[(size_t)node * NHEAD + hd];

    float4 acc0 = make_float4(0.f, 0.f, 0.f, 0.f);
    float4 acc1 = make_float4(0.f, 0.f, 0.f, 0.f);
    float4 acc2 = make_float4(0.f, 0.f, 0.f, 0.f);
    float4 acc3 = make_float4(0.f, 0.f, 0.f, 0.f);
    float s0 = 0.f, s1 = 0.f, s2 = 0.f, s3 = 0.f;

    int k = start;
    for (; k + 4 <= end; k += 4) {
        int sj0 = csr_src[k];
        int sj1 = csr_src[k + 1];
        int sj2 = csr_src[k + 2];
        int sj3 = csr_src[k + 3];
        float a0 = a_src[(size_t)sj0 * NHEAD + hd];
        float a1 = a_src[(size_t)sj1 * NHEAD + hd];
        float a2 = a_src[(size_t)sj2 * NHEAD + hd];
        float a3 = a_src[(size_t)sj3 * NHEAD + hd];
        ushort4 h0 = *(const ushort4*)(hb + ((size_t)sj0 << 8) + 4 * l);
        ushort4 h1 = *(const ushort4*)(hb + ((size_t)sj1 << 8) + 4 * l);
        ushort4 h2 = *(const ushort4*)(hb + ((size_t)sj2 << 8) + 4 * l);
        ushort4 h3 = *(const ushort4*)(hb + ((size_t)sj3 << 8) + 4 * l);
        float e0 = a0 + adh; e0 = fmaxf(e0, NEG_SLOPE * e0); float w0 = __expf(e0);
        float e1 = a1 + adh; e1 = fmaxf(e1, NEG_SLOPE * e1); float w1 = __expf(e1);
        float e2 = a2 + adh; e2 = fmaxf(e2, NEG_SLOPE * e2); float w2 = __expf(e2);
        float e3 = a3 + adh; e3 = fmaxf(e3, NEG_SLOPE * e3); float w3 = __expf(e3);
        s0 += w0; s1 += w1; s2 += w2; s3 += w3;
        acc0.x += w0 * bf2f(h0.x); acc0.y += w0 * bf2f(h0.y);
        acc0.z += w0 * bf2f(h0.z); acc0.w += w0 * bf2f(h0.w);
        acc1.x += w1 * bf2f(h1.x); acc1.y += w1 * bf2f(h1.y);
        acc1.z += w1 * bf2f(h1.z); acc1.w += w1 * bf2f(h1.w);
        acc2.x += w2 * bf2f(h2.x); acc2.y += w2 * bf2f(h2.y);
        acc2.z += w2 * bf2f(h2.z); acc2.w += w2 * bf2f(h2.w);
        acc3.x += w3 * bf2f(h3.x); acc3.y += w3 * bf2f(h3.y);
        acc3.z += w3 * bf2f(h3.z); acc3.w += w3 * bf2f(h3.w);
    }
    for (; k < end; ++k) {                       // tail (<=3 edges)
        int sj0 = csr_src[k];
        float a0 = a_src[(size_t)sj0 * NHEAD + hd];
        ushort4 h0 = *(const ushort4*)(hb + ((size_t)sj0 << 8) + 4 * l);
        float e0 = a0 + adh; e0 = fmaxf(e0, NEG_SLOPE * e0);
        float w0 = __expf(e0);
        s0 += w0;
        acc0.x += w0 * bf2f(h0.x); acc0.y += w0 * bf2f(h0.y);
        acc0.z += w0 * bf2f(h0.z); acc0.w += w0 * bf2f(h0.w);
    }

    float inv = 1.0f / (s0 + s1 + s2 + s3);      // per-head softmax denominator
    float4 acc;
    acc.x = (acc0.x + acc1.x + acc2.x + acc3.x) * inv;
    acc.y = (acc0.y + acc1.y + acc2.y + acc3.y) * inv;
    acc.z = (acc0.z + acc1.z + acc2.z + acc3.z) * inv;
    acc.w = (acc0.w + acc1.w + acc2.w + acc3.w) * inv;

    // reduce over heads: lanes l, l^16, l^32, l^48 hold same channels
    #pragma unroll
    for (int off = 16; off < 64; off <<= 1) {
        acc.x += __shfl_xor(acc.x, off, 64);
        acc.y += __shfl_xor(acc.y, off, 64);
        acc.z += __shfl_xor(acc.z, off, 64);
        acc.w += __shfl_xor(acc.w, off, 64);
    }
    if (l < 16) {
        float4 b4 = *(const float4*)(bias + 4 * l);
        float4 o;
        o.x = acc.x * 0.25f + b4.x;
        o.y = acc.y * 0.25f + b4.y;
        o.z = acc.z * 0.25f + b4.z;
        o.w = acc.w * 0.25f + b4.w;
        o.x = (o.x > 0.f) ? o.x : (__expf(o.x) - 1.f);
        o.y = (o.y > 0.f) ? o.y : (__expf(o.y) - 1.f);
        o.z = (o.z > 0.f) ? o.z : (__expf(o.z) - 1.f);
        o.w = (o.w > 0.f) ? o.w : (__expf(o.w) - 1.f);
        *(float4*)(out + (size_t)node * CH + 4 * l) = o;
    }
}

extern "C" void kernel_launch(void* const* d_in, const int* in_sizes, int n_in,
                              void* d_out, int out_size, void* d_ws, size_t ws_size,
                              hipStream_t stream)
{
    const float* x         = (const float*)d_in[0];
    const int*   edge_idx  = (const int*)d_in[1];
    const float* W         = (const float*)d_in[2];
    const float* att_src   = (const float*)d_in[3];
    const float* att_dst   = (const float*)d_in[4];
    const float* bias      = (const float*)d_in[5];
    float* out = (float*)d_out;

    const int N = in_sizes[0] / IN_F;
    const int E = in_sizes[1] / 2;
    const int Etot = E + N;
    const int NB = (N + 255) >> 8;     // coarse buckets (assumes N <= 65536)
    const int* srcp = edge_idx;
    const int* dstp = edge_idx + E;

    char* ws = (char*)d_ws;
    size_t off = 0;
    ushort*  hb     = (ushort*)(ws + off);   off += align256((size_t)N * HC * sizeof(ushort));
    float*   a_src  = (float*)(ws + off);    off += align256((size_t)N * NHEAD * sizeof(float));
    float*   a_dst  = (float*)(ws + off);    off += align256((size_t)N * NHEAD * sizeof(float));
    int*     ccnt   = (int*)(ws + off);      off += align256(256 * sizeof(int));
    int*     ebase  = (int*)(ws + off);      off += align256(257 * sizeof(int));
    int*     bcur   = (int*)(ws + off);      off += align256(256 * sizeof(int));
    unsigned* ebuf  = (unsigned*)(ws + off); off += align256((size_t)E * sizeof(unsigned));
    int*     rowptr = (int*)(ws + off);      off += align256(((size_t)N + 1) * sizeof(int));
    int*     csrs   = (int*)(ws + off);      off += align256((size_t)Etot * sizeof(int));
    (void)ws_size; (void)n_in; (void)out_size;

    const int PB = 416;
    const int epb = (E + PB - 1) / PB;

    dim3 gg((N + 63) / 64, NHEAD);
    gemm_mfma_kernel<<<gg, 256, 0, stream>>>(x, W, att_src, att_dst, hb,
                                             a_src, a_dst, ccnt, NB, N);
    bucket_count<<<PB, 256, 0, stream>>>(dstp, ccnt, E, epb, NB);
    scan_coarse<<<1, 256, 0, stream>>>(ccnt, ebase, bcur, rowptr, NB, N, E);
    bucket_scatter<<<PB, 256, 0, stream>>>(srcp, dstp, bcur, ebuf, E, epb, NB);
    csr_build<<<NB, 256, 0, stream>>>(ebuf, ebase, rowptr, csrs, N);
    aggregate_kernel<<<((size_t)N * 64 + 255) / 256, 256, 0, stream>>>(
        hb, a_src, a_dst, rowptr, csrs, bias, out, N);
}

// Round 6
// 210.140 us; speedup vs baseline: 1.7599x; 1.0191x over previous
//
#include <hip/hip_runtime.h>

#define NEG_SLOPE 0.2f
static constexpr int IN_F = 128;   // input feature dim
static constexpr int NHEAD = 4;
static constexpr int CH = 64;      // channels per head
static constexpr int HC = 256;     // NHEAD*CH

static __host__ size_t align256(size_t v) { return (v + 255) & ~((size_t)255); }

__device__ inline ushort f2bf(float f) {          // round-to-nearest-even fp32->bf16
    unsigned u = __float_as_uint(f);
    unsigned r = u + 0x7FFFu + ((u >> 16) & 1u);
    return (ushort)(r >> 16);
}
__device__ inline float bf2f(ushort s) { return __uint_as_float(((unsigned)s) << 16); }

typedef short s16x8 __attribute__((ext_vector_type(8)));    // 8 bf16 = 4 VGPR
typedef float f32x16 __attribute__((ext_vector_type(16)));  // 32x32 accumulator

// ---- prep: Wt[n][k] = bf16(W[k][n]) (256x128), + zero coarse counters ------
__global__ __launch_bounds__(256) void prep_kernel(
    const float* __restrict__ W, ushort* __restrict__ Wt,
    int* __restrict__ coarse_cnt)
{
    int f = blockIdx.x * 256 + threadIdx.x;     // 32768 elements
    int k = f >> 8;                             // 0..127
    int n = f & 255;                            // 0..255
    Wt[n * IN_F + k] = f2bf(W[(size_t)k * HC + n]);
    if (blockIdx.x == 0) coarse_cnt[threadIdx.x] = 0;
}

// ---- MFMA GEMM (2 heads/block) + fused edge bucket-count -------------------
// grid ((NTB + PBC), 2). Blocks with blockIdx.x < NTB: GEMM tile
// (64 rows x 128 cols = heads 2*by, 2*by+1). Blocks beyond: histogram a slice
// of the edge-dst array into coarse_cnt (bucket = dst>>8).
__global__ __launch_bounds__(256) void gemm_mfma_kernel(
    const float* __restrict__ x, const ushort* __restrict__ Wt,
    const float* __restrict__ att_src, const float* __restrict__ att_dst,
    ushort* __restrict__ hb, float* __restrict__ a_src, float* __restrict__ a_dst,
    const int* __restrict__ dst, int* __restrict__ coarse_cnt,
    int E, int epb, int NTB, int NB, int N)
{
    constexpr int LDK = 136;            // padded K stride (ushort elems)
    __shared__ ushort As[64 * LDK];     // x tile [m][k] bf16 (8704 ushorts)
    __shared__ ushort Bs[128 * LDK];    // Wt tile [n][k] bf16
    ushort* Hs = As;                    // 64 x 136 h-tile aliases As after MFMA

    const int t = threadIdx.x;

    if (blockIdx.x >= NTB) {            // ---- bucket-count role ----
        int* hist = (int*)As;
        hist[t] = 0;
        __syncthreads();
        int slice = (blockIdx.x - NTB) * 2 + blockIdx.y;
        int lo = slice * epb;
        int hi = min(E, lo + epb);
        for (int i = lo + t; i < hi; i += 256)
            atomicAdd(&hist[((unsigned)dst[i]) >> 8], 1);
        __syncthreads();
        if (t < NB && hist[t]) atomicAdd(&coarse_cnt[t], hist[t]);
        return;
    }

    const int m0 = blockIdx.x * 64;
    const int n0 = blockIdx.y * 128;    // col offset in h (2 heads)

    // stage A: x tile 64x128 fp32 -> bf16 (coalesced float4 loads, b64 writes)
    #pragma unroll
    for (int u = 0; u < 8; ++u) {
        int f = t + 256 * u;            // 2048 float4s
        int r = f >> 5;                 // row 0..63
        int k4 = (f & 31) * 4;          // k 0..124
        int row = m0 + r;
        float4 v = make_float4(0.f, 0.f, 0.f, 0.f);
        if (row < N) v = *(const float4*)(x + (size_t)row * IN_F + k4);
        ushort4 o;
        o.x = f2bf(v.x); o.y = f2bf(v.y); o.z = f2bf(v.z); o.w = f2bf(v.w);
        *(ushort4*)&As[r * LDK + k4] = o;
    }
    // stage B: Wt rows n0..n0+127 (bf16, coalesced uint4 loads, b128 writes)
    #pragma unroll
    for (int u = 0; u < 8; ++u) {
        int f = t + 256 * u;            // 2048 ushort8s: 128 n x 16 k-octs
        int n = f >> 4;                 // 0..127
        int k8 = (f & 15) * 8;          // 0..120
        uint4 v = *(const uint4*)(Wt + (size_t)(n0 + n) * IN_F + k8);
        *(uint4*)&Bs[n * LDK + k8] = v;
    }
    __syncthreads();

    const int w = t >> 6;
    const int lane = t & 63;
    const int mrow = 32 * (w >> 1) + (lane & 31);
    const int nbase = 64 * (w & 1) + (lane & 31);
    const int kq = (lane >> 5) * 8;     // 0 or 8

    f32x16 acc0 = {}, acc1 = {};
    #pragma unroll
    for (int s = 0; s < 8; ++s) {       // K = 8 x 16
        s16x8 af = *(const s16x8*)&As[mrow * LDK + 16 * s + kq];
        s16x8 b0 = *(const s16x8*)&Bs[nbase * LDK + 16 * s + kq];
        s16x8 b1 = *(const s16x8*)&Bs[(nbase + 32) * LDK + 16 * s + kq];
        acc0 = __builtin_amdgcn_mfma_f32_32x32x16_bf16(af, b0, acc0, 0, 0, 0);
        acc1 = __builtin_amdgcn_mfma_f32_32x32x16_bf16(af, b1, acc1, 0, 0, 0);
    }
    __syncthreads();                    // done reading As/Bs; Hs aliases As

    // acc -> LDS h tile. C layout: col=lane&31, row=(r&3)+8*(r>>2)+4*(lane>>5)
    {
        int rbase = 4 * (lane >> 5) + 32 * (w >> 1);
        int c0 = 64 * (w & 1) + (lane & 31);
        #pragma unroll
        for (int r = 0; r < 16; ++r) {
            int rowL = rbase + (r & 3) + 8 * (r >> 2);
            Hs[rowL * LDK + c0]      = f2bf(acc0[r]);
            Hs[rowL * LDK + c0 + 32] = f2bf(acc1[r]);
        }
    }
    __syncthreads();

    // coalesced h store + fused att dots. thread t: row t>>2, 32-col chunk t&3
    {
        int r2 = t >> 2;
        int q = t & 3;                  // 32-col chunk within 128
        int row = m0 + r2;
        uint4 p0 = *(const uint4*)&Hs[r2 * LDK + 32 * q];
        uint4 p1 = *(const uint4*)&Hs[r2 * LDK + 32 * q + 8];
        uint4 p2 = *(const uint4*)&Hs[r2 * LDK + 32 * q + 16];
        uint4 p3 = *(const uint4*)&Hs[r2 * LDK + 32 * q + 24];
        if (row < N) {
            ushort* dsth = hb + (size_t)row * HC + n0 + 32 * q;
            *(uint4*)(dsth)      = p0;
            *(uint4*)(dsth + 8)  = p1;
            *(uint4*)(dsth + 16) = p2;
            *(uint4*)(dsth + 24) = p3;
        }
        int hq = 2 * blockIdx.y + (q >> 1);      // global head of this chunk
        int cb = (q & 1) * 32;                   // channel base within head
        const float* asp = att_src + hq * CH + cb;
        const float* adp = att_dst + hq * CH + cb;
        unsigned uu[16] = { p0.x, p0.y, p0.z, p0.w, p1.x, p1.y, p1.z, p1.w,
                            p2.x, p2.y, p2.z, p2.w, p3.x, p3.y, p3.z, p3.w };
        float ps = 0.f, pd = 0.f;
        #pragma unroll
        for (int i = 0; i < 16; ++i) {
            float lo = bf2f((ushort)(uu[i] & 0xFFFFu));
            float hi = bf2f((ushort)(uu[i] >> 16));
            ps += lo * asp[2 * i] + hi * asp[2 * i + 1];
            pd += lo * adp[2 * i] + hi * adp[2 * i + 1];
        }
        ps += __shfl_xor(ps, 1, 64);    // combine the two chunks of a head
        pd += __shfl_xor(pd, 1, 64);
        if ((q & 1) == 0 && row < N) {
            a_src[(size_t)row * NHEAD + hq] = ps;
            a_dst[(size_t)row * NHEAD + hq] = pd;
        }
    }
}

// pass 2: scan of coarse counts (NB <= 256, one block)
__global__ __launch_bounds__(256) void scan_coarse(
    const int* __restrict__ coarse_cnt, int* __restrict__ ebase,
    int* __restrict__ bucket_cur, int* __restrict__ rowptr,
    int NB, int N, int E)
{
    __shared__ int sm[256];
    int t = threadIdx.x;
    int v = (t < NB) ? coarse_cnt[t] : 0;
    sm[t] = v;
    __syncthreads();
    #pragma unroll
    for (int off = 1; off < 256; off <<= 1) {
        int a = sm[t];
        int b = (t >= off) ? sm[t - off] : 0;
        __syncthreads();
        sm[t] = a + b;
        __syncthreads();
    }
    int incl = sm[t];
    int excl = incl - v;
    if (t < NB) { ebase[t] = excl; bucket_cur[t] = excl; }
    if (t == NB - 1) ebase[NB] = incl;
    if (t == 0) rowptr[N] = E + N;
}

// pass 3: scatter edges into bucket regions. Per-block LDS histogram ->
// one reservation atomic per (block,bucket) -> LDS-atomic local offsets.
// Packed value: (src << 8) | (dst & 255)
__global__ __launch_bounds__(256) void bucket_scatter(
    const int* __restrict__ src, const int* __restrict__ dst,
    int* __restrict__ bucket_cur, unsigned* __restrict__ ebuf,
    int E, int epb, int NB)
{
    __shared__ int hist[256];
    __shared__ int base[256];
    int t = threadIdx.x;
    hist[t] = 0;
    __syncthreads();
    int lo = blockIdx.x * epb;
    int hi = min(E, lo + epb);
    for (int i = lo + t; i < hi; i += 256)
        atomicAdd(&hist[((unsigned)dst[i]) >> 8], 1);
    __syncthreads();
    if (t < NB && hist[t]) base[t] = atomicAdd(&bucket_cur[t], hist[t]);
    __syncthreads();
    hist[t] = 0;                        // reuse as local offset cursor
    __syncthreads();
    for (int i = lo + t; i < hi; i += 256) {
        unsigned d = (unsigned)dst[i];
        unsigned b = d >> 8;
        int off2 = atomicAdd(&hist[b], 1);
        ebuf[base[b] + off2] = (((unsigned)src[i]) << 8) | (d & 255u);
    }
}

// pass 4: per-bucket CSR finalize. One block per bucket; 256-bin LDS
// histogram + scan + LDS-cursor scatter. Self loop goes first in each segment.
__global__ __launch_bounds__(256) void csr_build(
    const unsigned* __restrict__ ebuf, const int* __restrict__ ebase,
    int* __restrict__ rowptr, int* __restrict__ csr_src, int N)
{
    __shared__ int hist[256];
    __shared__ int scn[256];
    __shared__ int cur[256];
    int b = blockIdx.x;
    int t = threadIdx.x;
    int n0 = b << 8;
    int ncnt = min(256, N - n0);
    int lo = ebase[b], hi = ebase[b + 1];
    int cb = lo + n0;                   // global csr base (n0 = self loops before)
    hist[t] = 0;
    __syncthreads();
    for (int i = lo + t; i < hi; i += 256)
        atomicAdd(&hist[ebuf[i] & 255u], 1);
    __syncthreads();
    int v = hist[t];
    scn[t] = v;
    __syncthreads();
    #pragma unroll
    for (int off = 1; off < 256; off <<= 1) {
        int a = scn[t];
        int bb = (t >= off) ? scn[t - off] : 0;
        __syncthreads();
        scn[t] = a + bb;
        __syncthreads();
    }
    int excl = scn[t] - v;
    int segstart = cb + excl + t;       // +t = self loops of prior nodes
    if (t < ncnt) {
        rowptr[n0 + t] = segstart;
        csr_src[segstart] = n0 + t;     // self loop first
    }
    cur[t] = excl + t + 1;              // local cursor, skip self slot
    __syncthreads();
    for (int i = lo + t; i < hi; i += 256) {
        unsigned e = ebuf[i];
        int ln = (int)(e & 255u);
        int pos = atomicAdd(&cur[ln], 1);
        csr_src[cb + pos] = (int)(e >> 8);
    }
}

// ------------- single-pass softmax aggregate (no max subtraction) -----------
// Logits e = leaky_relu(a_src+a_dst) are O(±10): exp() cannot overflow fp32.
// One wave per node; lane l: head l>>4, channels 4*(l&15)..+3.
// 8-wide gather batches into 4 accumulators for memory-level parallelism.
__global__ __launch_bounds__(256) void aggregate_kernel(
    const ushort* __restrict__ hb, const float* __restrict__ a_src,
    const float* __restrict__ a_dst, const int* __restrict__ rowptr,
    const int* __restrict__ csr_src, const float* __restrict__ bias,
    float* __restrict__ out, int N)
{
    int node = (int)((blockIdx.x * (size_t)blockDim.x + threadIdx.x) >> 6);
    int l = threadIdx.x & 63;
    if (node >= N) return;
    int start = rowptr[node];
    int end = rowptr[node + 1];
    int hd = l >> 4;
    float adh = a_dst[(size_t)node * NHEAD + hd];

    float4 acc[4];
    float s[4];
    #pragma unroll
    for (int u = 0; u < 4; ++u) { acc[u] = make_float4(0.f,0.f,0.f,0.f); s[u] = 0.f; }

    int k = start;
    for (; k + 8 <= end; k += 8) {
        int sj[8];
        #pragma unroll
        for (int u = 0; u < 8; ++u) sj[u] = csr_src[k + u];
        float av[8]; ushort4 hv[8];
        #pragma unroll
        for (int u = 0; u < 8; ++u) {
            av[u] = a_src[(size_t)sj[u] * NHEAD + hd];
            hv[u] = *(const ushort4*)(hb + ((size_t)sj[u] << 8) + 4 * l);
        }
        #pragma unroll
        for (int u = 0; u < 8; ++u) {
            float e = av[u] + adh; e = fmaxf(e, NEG_SLOPE * e);
            float wgt = __expf(e);
            int q = u & 3;
            s[q] += wgt;
            acc[q].x += wgt * bf2f(hv[u].x); acc[q].y += wgt * bf2f(hv[u].y);
            acc[q].z += wgt * bf2f(hv[u].z); acc[q].w += wgt * bf2f(hv[u].w);
        }
    }
    for (; k + 4 <= end; k += 4) {
        int sj[4];
        #pragma unroll
        for (int u = 0; u < 4; ++u) sj[u] = csr_src[k + u];
        float av[4]; ushort4 hv[4];
        #pragma unroll
        for (int u = 0; u < 4; ++u) {
            av[u] = a_src[(size_t)sj[u] * NHEAD + hd];
            hv[u] = *(const ushort4*)(hb + ((size_t)sj[u] << 8) + 4 * l);
        }
        #pragma unroll
        for (int u = 0; u < 4; ++u) {
            float e = av[u] + adh; e = fmaxf(e, NEG_SLOPE * e);
            float wgt = __expf(e);
            s[u] += wgt;
            acc[u].x += wgt * bf2f(hv[u].x); acc[u].y += wgt * bf2f(hv[u].y);
            acc[u].z += wgt * bf2f(hv[u].z); acc[u].w += wgt * bf2f(hv[u].w);
        }
    }
    for (; k < end; ++k) {                       // tail (<=3 edges)
        int sj0 = csr_src[k];
        float a0 = a_src[(size_t)sj0 * NHEAD + hd];
        ushort4 h0 = *(const ushort4*)(hb + ((size_t)sj0 << 8) + 4 * l);
        float e0 = a0 + adh; e0 = fmaxf(e0, NEG_SLOPE * e0);
        float w0 = __expf(e0);
        s[0] += w0;
        acc[0].x += w0 * bf2f(h0.x); acc[0].y += w0 * bf2f(h0.y);
        acc[0].z += w0 * bf2f(h0.z); acc[0].w += w0 * bf2f(h0.w);
    }

    float inv = 1.0f / (s[0] + s[1] + s[2] + s[3]);
    float4 a4;
    a4.x = (acc[0].x + acc[1].x + acc[2].x + acc[3].x) * inv;
    a4.y = (acc[0].y + acc[1].y + acc[2].y + acc[3].y) * inv;
    a4.z = (acc[0].z + acc[1].z + acc[2].z + acc[3].z) * inv;
    a4.w = (acc[0].w + acc[1].w + acc[2].w + acc[3].w) * inv;

    // reduce over heads: lanes l, l^16, l^32, l^48 hold same channels
    #pragma unroll
    for (int off = 16; off < 64; off <<= 1) {
        a4.x += __shfl_xor(a4.x, off, 64);
        a4.y += __shfl_xor(a4.y, off, 64);
        a4.z += __shfl_xor(a4.z, off, 64);
        a4.w += __shfl_xor(a4.w, off, 64);
    }
    if (l < 16) {
        float4 b4 = *(const float4*)(bias + 4 * l);
        float4 o;
        o.x = a4.x * 0.25f + b4.x;
        o.y = a4.y * 0.25f + b4.y;
        o.z = a4.z * 0.25f + b4.z;
        o.w = a4.w * 0.25f + b4.w;
        o.x = (o.x > 0.f) ? o.x : (__expf(o.x) - 1.f);
        o.y = (o.y > 0.f) ? o.y : (__expf(o.y) - 1.f);
        o.z = (o.z > 0.f) ? o.z : (__expf(o.z) - 1.f);
        o.w = (o.w > 0.f) ? o.w : (__expf(o.w) - 1.f);
        *(float4*)(out + (size_t)node * CH + 4 * l) = o;
    }
}

extern "C" void kernel_launch(void* const* d_in, const int* in_sizes, int n_in,
                              void* d_out, int out_size, void* d_ws, size_t ws_size,
                              hipStream_t stream)
{
    const float* x         = (const float*)d_in[0];
    const int*   edge_idx  = (const int*)d_in[1];
    const float* W         = (const float*)d_in[2];
    const float* att_src   = (const float*)d_in[3];
    const float* att_dst   = (const float*)d_in[4];
    const float* bias      = (const float*)d_in[5];
    float* out = (float*)d_out;

    const int N = in_sizes[0] / IN_F;
    const int E = in_sizes[1] / 2;
    const int Etot = E + N;
    const int NB = (N + 255) >> 8;     // coarse buckets (assumes N <= 65536)
    const int* srcp = edge_idx;
    const int* dstp = edge_idx + E;

    char* ws = (char*)d_ws;
    size_t off = 0;
    ushort*  hb     = (ushort*)(ws + off);   off += align256((size_t)N * HC * sizeof(ushort));
    ushort*  Wt     = (ushort*)(ws + off);   off += align256((size_t)HC * IN_F * sizeof(ushort));
    float*   a_src  = (float*)(ws + off);    off += align256((size_t)N * NHEAD * sizeof(float));
    float*   a_dst  = (float*)(ws + off);    off += align256((size_t)N * NHEAD * sizeof(float));
    int*     ccnt   = (int*)(ws + off);      off += align256(256 * sizeof(int));
    int*     ebase  = (int*)(ws + off);      off += align256(257 * sizeof(int));
    int*     bcur   = (int*)(ws + off);      off += align256(256 * sizeof(int));
    unsigned* ebuf  = (unsigned*)(ws + off); off += align256((size_t)E * sizeof(unsigned));
    int*     rowptr = (int*)(ws + off);      off += align256(((size_t)N + 1) * sizeof(int));
    int*     csrs   = (int*)(ws + off);      off += align256((size_t)Etot * sizeof(int));
    (void)ws_size; (void)n_in; (void)out_size;

    const int NTB = (N + 63) / 64;     // gemm tiles
    const int PBC = 208;               // fused count blocks (x2 in grid.y = 416 slices)
    const int epbc = (E + 2 * PBC - 1) / (2 * PBC);
    const int PB = 416;                // scatter blocks
    const int epb = (E + PB - 1) / PB;

    prep_kernel<<<IN_F * HC / 256, 256, 0, stream>>>(W, Wt, ccnt);
    dim3 gg(NTB + PBC, 2);
    gemm_mfma_kernel<<<gg, 256, 0, stream>>>(x, Wt, att_src, att_dst, hb,
                                             a_src, a_dst, dstp, ccnt,
                                             E, epbc, NTB, NB, N);
    scan_coarse<<<1, 256, 0, stream>>>(ccnt, ebase, bcur, rowptr, NB, N, E);
    bucket_scatter<<<PB, 256, 0, stream>>>(srcp, dstp, bcur, ebuf, E, epb, NB);
    csr_build<<<NB, 256, 0, stream>>>(ebuf, ebase, rowptr, csrs, N);
    aggregate_kernel<<<((size_t)N * 64 + 255) / 256, 256, 0, stream>>>(
        hb, a_src, a_dst, rowptr, csrs, bias, out, N);
}

// Round 7
// 203.828 us; speedup vs baseline: 1.8144x; 1.0310x over previous
//
#include <hip/hip_runtime.h>

#define NEG_SLOPE 0.2f
static constexpr int IN_F = 128;   // input feature dim
static constexpr int NHEAD = 4;
static constexpr int CH = 64;      // channels per head
static constexpr int HC = 256;     // NHEAD*CH
static constexpr int SC_EPB = 2000;  // edges per scatter block
static constexpr int CB_CAP = 6144;  // csr_build LDS sort capacity

static __host__ size_t align256(size_t v) { return (v + 255) & ~((size_t)255); }

__device__ inline ushort f2bf(float f) {          // round-to-nearest-even fp32->bf16
    unsigned u = __float_as_uint(f);
    unsigned r = u + 0x7FFFu + ((u >> 16) & 1u);
    return (ushort)(r >> 16);
}
__device__ inline float bf2f(ushort s) { return __uint_as_float(((unsigned)s) << 16); }

typedef short s16x8 __attribute__((ext_vector_type(8)));    // 8 bf16 = 4 VGPR
typedef float f32x16 __attribute__((ext_vector_type(16)));  // 32x32 accumulator

// ---- prep: Wt[n][k] = bf16(W[k][n]) (256x128), + zero coarse counters ------
__global__ __launch_bounds__(256) void prep_kernel(
    const float* __restrict__ W, ushort* __restrict__ Wt,
    int* __restrict__ coarse_cnt)
{
    int f = blockIdx.x * 256 + threadIdx.x;     // 32768 elements
    int k = f >> 8;                             // 0..127
    int n = f & 255;                            // 0..255
    Wt[n * IN_F + k] = f2bf(W[(size_t)k * HC + n]);
    if (blockIdx.x == 0) coarse_cnt[threadIdx.x] = 0;
}

// ---- MFMA GEMM (2 heads/block) + fused edge bucket-count -------------------
__global__ __launch_bounds__(256) void gemm_mfma_kernel(
    const float* __restrict__ x, const ushort* __restrict__ Wt,
    const float* __restrict__ att_src, const float* __restrict__ att_dst,
    ushort* __restrict__ hb, float* __restrict__ a_src, float* __restrict__ a_dst,
    const int* __restrict__ dst, int* __restrict__ coarse_cnt,
    int E, int epb, int NTB, int NB, int N)
{
    constexpr int LDK = 136;            // padded K stride (ushort elems)
    __shared__ ushort As[64 * LDK];     // x tile [m][k] bf16
    __shared__ ushort Bs[128 * LDK];    // Wt tile [n][k] bf16
    ushort* Hs = As;                    // h-tile aliases As after MFMA

    const int t = threadIdx.x;

    if (blockIdx.x >= NTB) {            // ---- bucket-count role ----
        int* hist = (int*)As;
        hist[t] = 0;
        __syncthreads();
        int slice = (blockIdx.x - NTB) * 2 + blockIdx.y;
        int lo = slice * epb;
        int hi = min(E, lo + epb);
        for (int i = lo + t; i < hi; i += 256)
            atomicAdd(&hist[((unsigned)dst[i]) >> 8], 1);
        __syncthreads();
        if (t < NB && hist[t]) atomicAdd(&coarse_cnt[t], hist[t]);
        return;
    }

    const int m0 = blockIdx.x * 64;
    const int n0 = blockIdx.y * 128;    // col offset in h (2 heads)

    // stage A: x tile 64x128 fp32 -> bf16
    #pragma unroll
    for (int u = 0; u < 8; ++u) {
        int f = t + 256 * u;
        int r = f >> 5;
        int k4 = (f & 31) * 4;
        int row = m0 + r;
        float4 v = make_float4(0.f, 0.f, 0.f, 0.f);
        if (row < N) v = *(const float4*)(x + (size_t)row * IN_F + k4);
        ushort4 o;
        o.x = f2bf(v.x); o.y = f2bf(v.y); o.z = f2bf(v.z); o.w = f2bf(v.w);
        *(ushort4*)&As[r * LDK + k4] = o;
    }
    // stage B: Wt rows n0..n0+127
    #pragma unroll
    for (int u = 0; u < 8; ++u) {
        int f = t + 256 * u;
        int n = f >> 4;
        int k8 = (f & 15) * 8;
        uint4 v = *(const uint4*)(Wt + (size_t)(n0 + n) * IN_F + k8);
        *(uint4*)&Bs[n * LDK + k8] = v;
    }
    __syncthreads();

    const int w = t >> 6;
    const int lane = t & 63;
    const int mrow = 32 * (w >> 1) + (lane & 31);
    const int nbase = 64 * (w & 1) + (lane & 31);
    const int kq = (lane >> 5) * 8;

    f32x16 acc0 = {}, acc1 = {};
    #pragma unroll
    for (int s = 0; s < 8; ++s) {
        s16x8 af = *(const s16x8*)&As[mrow * LDK + 16 * s + kq];
        s16x8 b0 = *(const s16x8*)&Bs[nbase * LDK + 16 * s + kq];
        s16x8 b1 = *(const s16x8*)&Bs[(nbase + 32) * LDK + 16 * s + kq];
        acc0 = __builtin_amdgcn_mfma_f32_32x32x16_bf16(af, b0, acc0, 0, 0, 0);
        acc1 = __builtin_amdgcn_mfma_f32_32x32x16_bf16(af, b1, acc1, 0, 0, 0);
    }
    __syncthreads();

    // acc -> LDS h tile. C layout: col=lane&31, row=(r&3)+8*(r>>2)+4*(lane>>5)
    {
        int rbase = 4 * (lane >> 5) + 32 * (w >> 1);
        int c0 = 64 * (w & 1) + (lane & 31);
        #pragma unroll
        for (int r = 0; r < 16; ++r) {
            int rowL = rbase + (r & 3) + 8 * (r >> 2);
            Hs[rowL * LDK + c0]      = f2bf(acc0[r]);
            Hs[rowL * LDK + c0 + 32] = f2bf(acc1[r]);
        }
    }
    __syncthreads();

    // coalesced h store + fused att dots
    {
        int r2 = t >> 2;
        int q = t & 3;
        int row = m0 + r2;
        uint4 p0 = *(const uint4*)&Hs[r2 * LDK + 32 * q];
        uint4 p1 = *(const uint4*)&Hs[r2 * LDK + 32 * q + 8];
        uint4 p2 = *(const uint4*)&Hs[r2 * LDK + 32 * q + 16];
        uint4 p3 = *(const uint4*)&Hs[r2 * LDK + 32 * q + 24];
        if (row < N) {
            ushort* dsth = hb + (size_t)row * HC + n0 + 32 * q;
            *(uint4*)(dsth)      = p0;
            *(uint4*)(dsth + 8)  = p1;
            *(uint4*)(dsth + 16) = p2;
            *(uint4*)(dsth + 24) = p3;
        }
        int hq = 2 * blockIdx.y + (q >> 1);
        int cb = (q & 1) * 32;
        const float* asp = att_src + hq * CH + cb;
        const float* adp = att_dst + hq * CH + cb;
        unsigned uu[16] = { p0.x, p0.y, p0.z, p0.w, p1.x, p1.y, p1.z, p1.w,
                            p2.x, p2.y, p2.z, p2.w, p3.x, p3.y, p3.z, p3.w };
        float ps = 0.f, pd = 0.f;
        #pragma unroll
        for (int i = 0; i < 16; ++i) {
            float lo = bf2f((ushort)(uu[i] & 0xFFFFu));
            float hi = bf2f((ushort)(uu[i] >> 16));
            ps += lo * asp[2 * i] + hi * asp[2 * i + 1];
            pd += lo * adp[2 * i] + hi * adp[2 * i + 1];
        }
        ps += __shfl_xor(ps, 1, 64);
        pd += __shfl_xor(pd, 1, 64);
        if ((q & 1) == 0 && row < N) {
            a_src[(size_t)row * NHEAD + hq] = ps;
            a_dst[(size_t)row * NHEAD + hq] = pd;
        }
    }
}

// pass 2: scan of coarse counts (NB <= 256, one block)
__global__ __launch_bounds__(256) void scan_coarse(
    const int* __restrict__ coarse_cnt, int* __restrict__ ebase,
    int* __restrict__ bucket_cur, int* __restrict__ rowptr,
    int NB, int N, int E)
{
    __shared__ int sm[256];
    int t = threadIdx.x;
    int v = (t < NB) ? coarse_cnt[t] : 0;
    sm[t] = v;
    __syncthreads();
    #pragma unroll
    for (int off = 1; off < 256; off <<= 1) {
        int a = sm[t];
        int b = (t >= off) ? sm[t - off] : 0;
        __syncthreads();
        sm[t] = a + b;
        __syncthreads();
    }
    int incl = sm[t];
    int excl = incl - v;
    if (t < NB) { ebase[t] = excl; bucket_cur[t] = excl; }
    if (t == NB - 1) ebase[NB] = incl;
    if (t == 0) rowptr[N] = E + N;
}

// pass 3: scatter edges into bucket regions via block-local LDS counting sort,
// then emit contiguous per-bucket runs (coalesced; ~1 writer block per line).
// Packed value: (src << 8) | (dst & 255)
__global__ __launch_bounds__(256) void bucket_scatter(
    const int* __restrict__ src, const int* __restrict__ dst,
    int* __restrict__ bucket_cur, unsigned* __restrict__ ebuf,
    int E, int NB)
{
    __shared__ int hist[256];
    __shared__ int lbase[256];
    __shared__ int gbase[256];
    __shared__ int cur[256];
    __shared__ unsigned sbuf[SC_EPB + 48];
    __shared__ unsigned char tb[SC_EPB + 48];
    int t = threadIdx.x;
    int lo = blockIdx.x * SC_EPB;
    int hi = min(E, lo + SC_EPB);
    int cnt = hi - lo;
    hist[t] = 0;
    __syncthreads();
    unsigned pk[8]; int bk[8];
    #pragma unroll
    for (int u = 0; u < 8; ++u) {
        int i = lo + t + 256 * u;
        bk[u] = -1;
        if (i < hi) {
            unsigned d = (unsigned)dst[i];
            bk[u] = (int)(d >> 8);
            pk[u] = (((unsigned)src[i]) << 8) | (d & 255u);
            atomicAdd(&hist[bk[u]], 1);
        }
    }
    __syncthreads();
    int v = hist[t];
    lbase[t] = v;
    __syncthreads();
    #pragma unroll
    for (int off = 1; off < 256; off <<= 1) {
        int a = lbase[t];
        int b = (t >= off) ? lbase[t - off] : 0;
        __syncthreads();
        lbase[t] = a + b;
        __syncthreads();
    }
    int excl = lbase[t] - v;
    if (v) gbase[t] = atomicAdd(&bucket_cur[t], v);   // reserve global run
    __syncthreads();
    lbase[t] = excl;
    cur[t] = excl;
    __syncthreads();
    #pragma unroll
    for (int u = 0; u < 8; ++u) {
        if (bk[u] >= 0) {
            int p = atomicAdd(&cur[bk[u]], 1);
            sbuf[p] = pk[u];
            tb[p] = (unsigned char)bk[u];
        }
    }
    __syncthreads();
    for (int j = t; j < cnt; j += 256) {
        int b = tb[j];
        ebuf[gbase[b] + j - lbase[b]] = sbuf[j];
    }
}

// pass 4: per-bucket CSR finalize with LDS sort -> coalesced final writes.
// Self loop goes first in each node's segment.
__global__ __launch_bounds__(256) void csr_build(
    const unsigned* __restrict__ ebuf, const int* __restrict__ ebase,
    int* __restrict__ rowptr, int* __restrict__ csr_src, int N)
{
    __shared__ int hist[256];
    __shared__ int scn[256];
    __shared__ int cur[256];
    __shared__ unsigned srt[CB_CAP];
    int b = blockIdx.x;
    int t = threadIdx.x;
    int n0 = b << 8;
    int ncnt = min(256, N - n0);
    int lo = ebase[b], hi = ebase[b + 1];
    int cnt = hi - lo;
    int cb = lo + n0;                   // global csr base (n0 = self loops before)
    hist[t] = 0;
    __syncthreads();
    for (int i = lo + t; i < hi; i += 256)
        atomicAdd(&hist[ebuf[i] & 255u], 1);
    __syncthreads();
    int v = hist[t];
    scn[t] = v;
    __syncthreads();
    #pragma unroll
    for (int off = 1; off < 256; off <<= 1) {
        int a = scn[t];
        int bb = (t >= off) ? scn[t - off] : 0;
        __syncthreads();
        scn[t] = a + bb;
        __syncthreads();
    }
    int excl = scn[t] - v;
    if (t < ncnt) {
        int segstart = cb + excl + t;   // +t = self loops of prior nodes
        rowptr[n0 + t] = segstart;
        csr_src[segstart] = n0 + t;     // self loop first
    }
    cur[t] = excl;
    __syncthreads();
    if (cnt <= CB_CAP) {
        for (int i = lo + t; i < hi; i += 256) {
            unsigned e = ebuf[i];
            int p = atomicAdd(&cur[e & 255u], 1);
            srt[p] = e;
        }
        __syncthreads();
        for (int j = t; j < cnt; j += 256) {
            unsigned e = srt[j];
            csr_src[cb + j + (int)(e & 255u) + 1] = (int)(e >> 8);
        }
    } else {                            // fallback (oversized bucket)
        for (int i = lo + t; i < hi; i += 256) {
            unsigned e = ebuf[i];
            int ln = (int)(e & 255u);
            int p = atomicAdd(&cur[ln], 1);
            csr_src[cb + p + ln + 1] = (int)(e >> 8);
        }
    }
}

// ------------- single-pass softmax aggregate (no max subtraction) -----------
// Logits e = leaky_relu(a_src+a_dst) are O(±10): exp() cannot overflow fp32.
// One wave per node; lane l: head l>>4, channels 4*(l&15)..+3.
// 4-edge unroll, independent accumulators (VGPR 32, occupancy ~68%).
__global__ __launch_bounds__(256) void aggregate_kernel(
    const ushort* __restrict__ hb, const float* __restrict__ a_src,
    const float* __restrict__ a_dst, const int* __restrict__ rowptr,
    const int* __restrict__ csr_src, const float* __restrict__ bias,
    float* __restrict__ out, int N)
{
    int node = (int)((blockIdx.x * (size_t)blockDim.x + threadIdx.x) >> 6);
    int l = threadIdx.x & 63;
    if (node >= N) return;
    int start = rowptr[node];
    int end = rowptr[node + 1];
    int hd = l >> 4;
    float adh = a_dst[(size_t)node * NHEAD + hd];

    float4 acc0 = make_float4(0.f, 0.f, 0.f, 0.f);
    float4 acc1 = make_float4(0.f, 0.f, 0.f, 0.f);
    float4 acc2 = make_float4(0.f, 0.f, 0.f, 0.f);
    float4 acc3 = make_float4(0.f, 0.f, 0.f, 0.f);
    float s0 = 0.f, s1 = 0.f, s2 = 0.f, s3 = 0.f;

    int k = start;
    for (; k + 4 <= end; k += 4) {
        int sj0 = csr_src[k];
        int sj1 = csr_src[k + 1];
        int sj2 = csr_src[k + 2];
        int sj3 = csr_src[k + 3];
        float a0 = a_src[(size_t)sj0 * NHEAD + hd];
        float a1 = a_src[(size_t)sj1 * NHEAD + hd];
        float a2 = a_src[(size_t)sj2 * NHEAD + hd];
        float a3 = a_src[(size_t)sj3 * NHEAD + hd];
        ushort4 h0 = *(const ushort4*)(hb + ((size_t)sj0 << 8) + 4 * l);
        ushort4 h1 = *(const ushort4*)(hb + ((size_t)sj1 << 8) + 4 * l);
        ushort4 h2 = *(const ushort4*)(hb + ((size_t)sj2 << 8) + 4 * l);
        ushort4 h3 = *(const ushort4*)(hb + ((size_t)sj3 << 8) + 4 * l);
        float e0 = a0 + adh; e0 = fmaxf(e0, NEG_SLOPE * e0); float w0 = __expf(e0);
        float e1 = a1 + adh; e1 = fmaxf(e1, NEG_SLOPE * e1); float w1 = __expf(e1);
        float e2 = a2 + adh; e2 = fmaxf(e2, NEG_SLOPE * e2); float w2 = __expf(e2);
        float e3 = a3 + adh; e3 = fmaxf(e3, NEG_SLOPE * e3); float w3 = __expf(e3);
        s0 += w0; s1 += w1; s2 += w2; s3 += w3;
        acc0.x += w0 * bf2f(h0.x); acc0.y += w0 * bf2f(h0.y);
        acc0.z += w0 * bf2f(h0.z); acc0.w += w0 * bf2f(h0.w);
        acc1.x += w1 * bf2f(h1.x); acc1.y += w1 * bf2f(h1.y);
        acc1.z += w1 * bf2f(h1.z); acc1.w += w1 * bf2f(h1.w);
        acc2.x += w2 * bf2f(h2.x); acc2.y += w2 * bf2f(h2.y);
        acc2.z += w2 * bf2f(h2.z); acc2.w += w2 * bf2f(h2.w);
        acc3.x += w3 * bf2f(h3.x); acc3.y += w3 * bf2f(h3.y);
        acc3.z += w3 * bf2f(h3.z); acc3.w += w3 * bf2f(h3.w);
    }
    for (; k < end; ++k) {                       // tail (<=3 edges)
        int sj0 = csr_src[k];
        float a0 = a_src[(size_t)sj0 * NHEAD + hd];
        ushort4 h0 = *(const ushort4*)(hb + ((size_t)sj0 << 8) + 4 * l);
        float e0 = a0 + adh; e0 = fmaxf(e0, NEG_SLOPE * e0);
        float w0 = __expf(e0);
        s0 += w0;
        acc0.x += w0 * bf2f(h0.x); acc0.y += w0 * bf2f(h0.y);
        acc0.z += w0 * bf2f(h0.z); acc0.w += w0 * bf2f(h0.w);
    }

    float inv = 1.0f / (s0 + s1 + s2 + s3);      // per-head softmax denominator
    float4 acc;
    acc.x = (acc0.x + acc1.x + acc2.x + acc3.x) * inv;
    acc.y = (acc0.y + acc1.y + acc2.y + acc3.y) * inv;
    acc.z = (acc0.z + acc1.z + acc2.z + acc3.z) * inv;
    acc.w = (acc0.w + acc1.w + acc2.w + acc3.w) * inv;

    // reduce over heads: lanes l, l^16, l^32, l^48 hold same channels
    #pragma unroll
    for (int off = 16; off < 64; off <<= 1) {
        acc.x += __shfl_xor(acc.x, off, 64);
        acc.y += __shfl_xor(acc.y, off, 64);
        acc.z += __shfl_xor(acc.z, off, 64);
        acc.w += __shfl_xor(acc.w, off, 64);
    }
    if (l < 16) {
        float4 b4 = *(const float4*)(bias + 4 * l);
        float4 o;
        o.x = acc.x * 0.25f + b4.x;
        o.y = acc.y * 0.25f + b4.y;
        o.z = acc.z * 0.25f + b4.z;
        o.w = acc.w * 0.25f + b4.w;
        o.x = (o.x > 0.f) ? o.x : (__expf(o.x) - 1.f);
        o.y = (o.y > 0.f) ? o.y : (__expf(o.y) - 1.f);
        o.z = (o.z > 0.f) ? o.z : (__expf(o.z) - 1.f);
        o.w = (o.w > 0.f) ? o.w : (__expf(o.w) - 1.f);
        *(float4*)(out + (size_t)node * CH + 4 * l) = o;
    }
}

extern "C" void kernel_launch(void* const* d_in, const int* in_sizes, int n_in,
                              void* d_out, int out_size, void* d_ws, size_t ws_size,
                              hipStream_t stream)
{
    const float* x         = (const float*)d_in[0];
    const int*   edge_idx  = (const int*)d_in[1];
    const float* W         = (const float*)d_in[2];
    const float* att_src   = (const float*)d_in[3];
    const float* att_dst   = (const float*)d_in[4];
    const float* bias      = (const float*)d_in[5];
    float* out = (float*)d_out;

    const int N = in_sizes[0] / IN_F;
    const int E = in_sizes[1] / 2;
    const int Etot = E + N;
    const int NB = (N + 255) >> 8;     // coarse buckets (assumes N <= 65536)
    const int* srcp = edge_idx;
    const int* dstp = edge_idx + E;

    char* ws = (char*)d_ws;
    size_t off = 0;
    ushort*  hb     = (ushort*)(ws + off);   off += align256((size_t)N * HC * sizeof(ushort));
    ushort*  Wt     = (ushort*)(ws + off);   off += align256((size_t)HC * IN_F * sizeof(ushort));
    float*   a_src  = (float*)(ws + off);    off += align256((size_t)N * NHEAD * sizeof(float));
    float*   a_dst  = (float*)(ws + off);    off += align256((size_t)N * NHEAD * sizeof(float));
    int*     ccnt   = (int*)(ws + off);      off += align256(256 * sizeof(int));
    int*     ebase  = (int*)(ws + off);      off += align256(257 * sizeof(int));
    int*     bcur   = (int*)(ws + off);      off += align256(256 * sizeof(int));
    unsigned* ebuf  = (unsigned*)(ws + off); off += align256((size_t)E * sizeof(unsigned));
    int*     rowptr = (int*)(ws + off);      off += align256(((size_t)N + 1) * sizeof(int));
    int*     csrs   = (int*)(ws + off);      off += align256((size_t)Etot * sizeof(int));
    (void)ws_size; (void)n_in; (void)out_size;

    const int NTB = (N + 63) / 64;     // gemm tiles
    const int PBC = 208;               // fused count blocks (x2 = 416 slices)
    const int epbc = (E + 2 * PBC - 1) / (2 * PBC);
    const int PBS = (E + SC_EPB - 1) / SC_EPB;   // scatter blocks (=400)

    prep_kernel<<<IN_F * HC / 256, 256, 0, stream>>>(W, Wt, ccnt);
    dim3 gg(NTB + PBC, 2);
    gemm_mfma_kernel<<<gg, 256, 0, stream>>>(x, Wt, att_src, att_dst, hb,
                                             a_src, a_dst, dstp, ccnt,
                                             E, epbc, NTB, NB, N);
    scan_coarse<<<1, 256, 0, stream>>>(ccnt, ebase, bcur, rowptr, NB, N, E);
    bucket_scatter<<<PBS, 256, 0, stream>>>(srcp, dstp, bcur, ebuf, E, NB);
    csr_build<<<NB, 256, 0, stream>>>(ebuf, ebase, rowptr, csrs, N);
    aggregate_kernel<<<((size_t)N * 64 + 255) / 256, 256, 0, stream>>>(
        hb, a_src, a_dst, rowptr, csrs, bias, out, N);
}